// Round 1
// 325.923 us; speedup vs baseline: 1.0520x; 1.0520x over previous
//
#include <hip/hip_runtime.h>

// ---------------------------------------------------------------------------
// Attention (GQA + RoPE + softcap + causal) on gfx950, bf16 MFMA pipeline.
// B=2 T=2048 D=2048, NH=16 NKV=8 HD=128, softcap=50, causal.
// R5: k_gemm_qkv rewritten as 256x256-tile, BK=64, 512-thread 8-phase kernel
//     (10-slot 160KiB half-tile ring, counted vmcnt(4), raw barriers,
//     setprio around MFMA). RoPE/V-transpose epilogue done per head through
//     the ring reused as a [256][132] stash. k_prep/k_flash/k_gemm_out
//     unchanged.
// ---------------------------------------------------------------------------

typedef unsigned short u16;
typedef __attribute__((ext_vector_type(8))) short short8;   // 8 x bf16 (4 VGPRs)
typedef __attribute__((ext_vector_type(4))) float floatx4;  // MFMA acc

static __device__ __forceinline__ u16 f2b(float f){
  unsigned u = __float_as_uint(f);
  u = (u + 0x7fffu + ((u >> 16) & 1u)) >> 16;   // RNE
  return (u16)u;
}
static __device__ __forceinline__ float b2f(u16 u){
  return __uint_as_float(((unsigned)u) << 16);
}
// async global->LDS DMA, 16B per lane; LDS dest = wave-uniform base + lane*16
static __device__ __forceinline__ void gload16(const u16* g, u16* l){
  __builtin_amdgcn_global_load_lds(
      (const __attribute__((address_space(1))) unsigned int*)g,
      (__attribute__((address_space(3))) unsigned int*)l, 16, 0, 0);
}

// ---- prep: x->bf16 | w_q/w_kv/w_out transpose->B^T bf16 | sin/cos table ----
static __device__ void tr64(const float* __restrict__ s, u16* __restrict__ d,
                            int sRS, int dRS, float (*t)[65], int tid){
  #pragma unroll
  for(int i = 0; i < 16; i++){
    int idx = tid + 256 * i;
    t[idx >> 6][idx & 63] = s[(long)(idx >> 6) * sRS + (idx & 63)];
  }
  __syncthreads();
  #pragma unroll
  for(int i = 0; i < 16; i++){
    int idx = tid + 256 * i;
    d[(long)(idx >> 6) * dRS + (idx & 63)] = f2b(t[idx & 63][idx >> 6]);
  }
}

__global__ __launch_bounds__(256) void k_prep(
    const float* __restrict__ x, u16* __restrict__ xb,
    const float* __restrict__ wq, u16* __restrict__ wq_t,
    const float* __restrict__ wkv, u16* __restrict__ wkv_t,
    const float* __restrict__ wo, u16* __restrict__ wo_t,
    const int* __restrict__ pos, float* __restrict__ tab){
  __shared__ float t[64][65];
  int blk = blockIdx.x, tid = threadIdx.x;
  if(blk < 8192){                               // x fp32 -> bf16
    int i = blk * 256 + tid;
    float4 v = ((const float4*)x)[i];
    ushort4 o = make_ushort4(f2b(v.x), f2b(v.y), f2b(v.z), f2b(v.w));
    ((ushort4*)xb)[i] = o;
  } else if(blk < 9216){                        // w_q [16][2048][128] -> [16][128][2048]
    int q = blk - 8192;
    int bx = q & 1, by = (q >> 1) & 31, bz = q >> 6;
    tr64(wq + (long)bz * 262144 + (long)by * 64 * 128 + bx * 64,
         wq_t + (long)bz * 262144 + (long)bx * 64 * 2048 + by * 64, 128, 2048, t, tid);
  } else if(blk < 10240){                       // w_kv [16][2048][128] -> [16][128][2048]
    int q = blk - 9216;
    int bx = q & 1, by = (q >> 1) & 31, bz = q >> 6;
    tr64(wkv + (long)bz * 262144 + (long)by * 64 * 128 + bx * 64,
         wkv_t + (long)bz * 262144 + (long)bx * 64 * 2048 + by * 64, 128, 2048, t, tid);
  } else if(blk < 11264){                       // w_out [2048][2048] -> transpose
    int q = blk - 10240;
    int bx = q & 31, by = q >> 5;
    tr64(wo + (long)by * 64 * 2048 + bx * 64,
         wo_t + (long)bx * 64 * 2048 + by * 64, 2048, 2048, t, tid);
  } else {                                      // sin/cos: tab[row][0:64]=sin, [64:128]=cos
    int idx = (blk - 11264) * 256 + tid;        // 262,144 = 4096 rows x 64 h
    int row = idx >> 6, h = idx & 63;
    float pf = (float)pos[row];
    float inv = exp2f(-0.20762050593045077f * (float)h);  // 10000^(-h/64)
    float ang = pf * inv;
    tab[(row << 7) + h]      = sinf(ang);
    tab[(row << 7) + 64 + h] = cosf(ang);
  }
}

// ---- fused QKV projection GEMM + RoPE + V-transpose epilogue ---------------
// 256x256 tile, BK=64, 512 threads = 8 waves (2M x 4N), each wave owns a
// 128x64 output sub-tile (acc[8][4]). 8-phase schedule: per phase
// { ds_read frag subtile ; stage one 16KB half-tile ; barrier ; 16 MFMA ;
//   barrier }, staging through a unified 10-slot half-tile ring (160 KiB).
// Half-tile stream: half i (tile i>>2, h=i&3: 0,1=A-halves 2,3=B-halves) is
// issued at phase i; tile t computes at phases 4t+6..4t+9. Checkpoint
// vmcnt(4) once per K-tile (phase 4t+9) => tile t+1 fully landed, newest 2
// half-tiles may stay in flight. Every ring-slot reuse is >=1 barrier-
// separated phase after its last ds_read (WAR-safe). Tail stages clamp the
// source tile to 31 (dummy re-reads) so vmcnt accounting stays exact.
// nt<8 -> q heads 2nt,2nt+1 ; 8..11 -> k ; 12..15 -> v (transposed).
#define QKV_BAR() do{ __builtin_amdgcn_s_barrier(); \
                      __builtin_amdgcn_sched_barrier(0); }while(0)
#define STAGE_A(tt, h) do{ \
  const u16* s_ = Ag + (tt) * 64 + (h) * 262144; \
  u16* d_ = ld + ss * 8192; \
  gload16(s_, d_); gload16(s_ + 131072, d_ + 4096); \
  ss++; if(ss == 10) ss = 0; }while(0)
#define STAGE_B(tt, h) do{ \
  const u16* s_ = Bg + (tt) * 64 + (h) * 262144; \
  u16* d_ = ld + ss * 8192; \
  gload16(s_, d_); gload16(s_ + 131072, d_ + 4096); \
  ss++; if(ss == 10) ss = 0; }while(0)

__global__ __launch_bounds__(512, 2) void k_gemm_qkv(
    const u16* __restrict__ A, const u16* __restrict__ wq_t, const u16* __restrict__ wkv_t,
    const float* __restrict__ tab,
    u16* __restrict__ qb, u16* __restrict__ kb, u16* __restrict__ vtp){
  __shared__ __attribute__((aligned(16))) u16 ring[81920];  // 10 x 16KB = 160 KiB
  int mt = blockIdx.x, nt = blockIdx.y;
  const u16* Bt = (nt < 8) ? (wq_t + (long)nt * 524288)
                           : (wkv_t + (long)(nt - 8) * 524288);
  int tid = threadIdx.x;
  int lane = tid & 63, wave = tid >> 6, l15 = lane & 15, quad = lane >> 4;
  int wr = wave >> 2, wc = wave & 3;            // 2M x 4N wave grid
  int cq0 = quad ^ (l15 & 7), cq1 = cq0 ^ 4;    // swizzled chunk, ks=0 / ks=1
  int srow = tid >> 3;
  int gch  = (tid & 7) ^ (srow & 7);            // XOR-swizzled staging chunks
  const u16* Ag = A  + ((long)mt * 256 + srow) * 2048 + (gch << 3);
  const u16* Bg = Bt + (long)srow * 2048 + (gch << 3);
  u16* ld = ring + tid * 8;
  int aB = l15 << 6;                            // in-slot elem offsets
  int bB = ((wc & 1) * 64 + l15) << 6;
  int sa = wr;                                  // A-slot for tile t: (4t+wr)%10
  int sb = 2 + (wc >> 1);                       // B-slot: (4t+2+(wc>>1))%10
  int ss = 0;                                   // stage slot: phase % 10
  floatx4 acc[8][4];
  const floatx4 fz = {0.f, 0.f, 0.f, 0.f};
  #pragma unroll
  for(int m = 0; m < 8; m++)
    #pragma unroll
    for(int n = 0; n < 4; n++) acc[m][n] = fz;

  // prologue: halves 0..5 = A0(0) A1(0) B0(0) B1(0) A0(1) A1(1)
  STAGE_A(0, 0); STAGE_A(0, 1); STAGE_B(0, 0); STAGE_B(0, 1);
  STAGE_A(1, 0); STAGE_A(1, 1);
  asm volatile("s_waitcnt vmcnt(4)" ::: "memory");  // tile 0 landed
  QKV_BAR();

  #pragma unroll 1
  for(int t = 0; t < 32; t++){
    const u16* aS = ring + sa * 8192;
    const u16* bS = ring + sb * 8192;
    int tB = (t < 31) ? t + 1 : 31;             // clamped tail = dummy re-reads
    int tA = (t < 30) ? t + 2 : 31;
    short8 af[4], bfr[4];
    // ---- p0: ks=0, rows 0..63 --------------------------------------------
    #pragma unroll
    for(int n = 0; n < 4; n++) bfr[n] = *(const short8*)(bS + bB + (n << 10) + (cq0 << 3));
    #pragma unroll
    for(int m = 0; m < 4; m++) af[m]  = *(const short8*)(aS + aB + (m << 10) + (cq0 << 3));
    STAGE_B(tB, 0);
    QKV_BAR();
    __builtin_amdgcn_s_setprio(1);
    #pragma unroll
    for(int m = 0; m < 4; m++)
      #pragma unroll
      for(int n = 0; n < 4; n++)
        acc[m][n] = __builtin_amdgcn_mfma_f32_16x16x32_bf16(af[m], bfr[n], acc[m][n], 0, 0, 0);
    __builtin_amdgcn_s_setprio(0);
    QKV_BAR();
    // ---- p1: ks=0, rows 64..127 (reuse bfr) ------------------------------
    #pragma unroll
    for(int m = 0; m < 4; m++) af[m] = *(const short8*)(aS + aB + 4096 + (m << 10) + (cq0 << 3));
    STAGE_B(tB, 1);
    QKV_BAR();
    __builtin_amdgcn_s_setprio(1);
    #pragma unroll
    for(int m = 0; m < 4; m++)
      #pragma unroll
      for(int n = 0; n < 4; n++)
        acc[4 + m][n] = __builtin_amdgcn_mfma_f32_16x16x32_bf16(af[m], bfr[n], acc[4 + m][n], 0, 0, 0);
    __builtin_amdgcn_s_setprio(0);
    QKV_BAR();
    // ---- p2: ks=1, rows 0..63 --------------------------------------------
    #pragma unroll
    for(int n = 0; n < 4; n++) bfr[n] = *(const short8*)(bS + bB + (n << 10) + (cq1 << 3));
    #pragma unroll
    for(int m = 0; m < 4; m++) af[m]  = *(const short8*)(aS + aB + (m << 10) + (cq1 << 3));
    STAGE_A(tA, 0);
    QKV_BAR();
    __builtin_amdgcn_s_setprio(1);
    #pragma unroll
    for(int m = 0; m < 4; m++)
      #pragma unroll
      for(int n = 0; n < 4; n++)
        acc[m][n] = __builtin_amdgcn_mfma_f32_16x16x32_bf16(af[m], bfr[n], acc[m][n], 0, 0, 0);
    __builtin_amdgcn_s_setprio(0);
    QKV_BAR();
    // ---- p3: ks=1, rows 64..127 (reuse bfr) + per-K-tile checkpoint ------
    #pragma unroll
    for(int m = 0; m < 4; m++) af[m] = *(const short8*)(aS + aB + 4096 + (m << 10) + (cq1 << 3));
    STAGE_A(tA, 1);
    asm volatile("s_waitcnt vmcnt(4)" ::: "memory");  // tile t+1 fully landed
    __builtin_amdgcn_sched_barrier(0);
    QKV_BAR();
    __builtin_amdgcn_s_setprio(1);
    #pragma unroll
    for(int m = 0; m < 4; m++)
      #pragma unroll
      for(int n = 0; n < 4; n++)
        acc[4 + m][n] = __builtin_amdgcn_mfma_f32_16x16x32_bf16(af[m], bfr[n], acc[4 + m][n], 0, 0, 0);
    __builtin_amdgcn_s_setprio(0);
    QKV_BAR();
    sa += 4; if(sa >= 10) sa -= 10;
    sb += 4; if(sb >= 10) sb -= 10;
  }

  // ---- epilogue: drain DMAs, reuse ring as sT[256][132], rope/v-transpose
  asm volatile("s_waitcnt vmcnt(0)" ::: "memory");
  __syncthreads();
  u16* sT = ring;
  int grow0 = mt * 256;
  int hb = wc >> 1, wcl = wc & 1;
  #pragma unroll 1
  for(int hh = 0; hh < 2; hh++){                // two heads per 256-wide tile
    if(hb == hh){                               // stash this head's columns
      #pragma unroll
      for(int m = 0; m < 8; m++){
        int row = wr * 128 + m * 16 + quad * 4;
        #pragma unroll
        for(int n = 0; n < 4; n++){
          int colh = wcl * 64 + n * 16 + l15;
          #pragma unroll
          for(int j = 0; j < 4; j++)
            sT[(row + j) * 132 + colh] = f2b(acc[m][n][j]);
        }
      }
    }
    __syncthreads();
    if(nt < 12){                                // q or k: rope(+scale)
      float scale = (nt < 8) ? 0.08838834764831845f : 1.0f;
      u16* dst = (nt < 8) ? qb : kb;
      int dS   = (nt < 8) ? 2048 : 1024;
      int dcol = (nt < 8) ? (nt * 2 + hh) * 128 : ((nt - 8) * 2 + hh) * 128;
      #pragma unroll
      for(int it = 0; it < 16; it++){
        int idx = tid + 512 * it;               // 8192 u32 pair-words
        int row = idx >> 5, cw = idx & 31;
        int grow = grow0 + row;
        unsigned lo = *(const unsigned*)&sT[row * 132 + 2 * cw];
        unsigned hi = *(const unsigned*)&sT[row * 132 + 64 + 2 * cw];
        float2 sn = *(const float2*)&tab[(grow << 7) + 2 * cw];
        float2 cs = *(const float2*)&tab[(grow << 7) + 64 + 2 * cw];
        float x1a = b2f((u16)lo), x1b = b2f((u16)(lo >> 16));
        float x2a = b2f((u16)hi), x2b = b2f((u16)(hi >> 16));
        float o1a = (x1a * cs.x - x2a * sn.x) * scale;
        float o1b = (x1b * cs.y - x2b * sn.y) * scale;
        float o2a = (x2a * cs.x + x1a * sn.x) * scale;
        float o2b = (x2b * cs.y + x1b * sn.y) * scale;
        unsigned w1 = (unsigned)f2b(o1a) | ((unsigned)f2b(o1b) << 16);
        unsigned w2 = (unsigned)f2b(o2a) | ((unsigned)f2b(o2b) << 16);
        *(unsigned*)&dst[(long)grow * dS + dcol + 2 * cw] = w1;
        *(unsigned*)&dst[(long)grow * dS + dcol + 64 + 2 * cw] = w2;
      }
    } else {                                    // v: transposed -> v_t[b][kv][h][s]
      int b = mt >> 3, kvh = (nt - 12) * 2 + hh;
      u16* vt = vtp + (long)(b * 8 + kvh) * 262144;
      int tcol0 = (mt & 7) * 256;
      int h = tid >> 2, s0 = (tid & 3) * 64;
      #pragma unroll
      for(int i = 0; i < 16; i++){
        int s = s0 + i * 4;
        ushort4 v4 = make_ushort4(sT[(s    ) * 132 + h], sT[(s + 1) * 132 + h],
                                  sT[(s + 2) * 132 + h], sT[(s + 3) * 132 + h]);
        *(ushort4*)&vt[(long)h * 2048 + tcol0 + s] = v4;
      }
    }
    __syncthreads();
  }
}
#undef STAGE_A
#undef STAGE_B
#undef QKV_BAR

// ---- out projection GEMM: enc[4096x2048] x w_out^T -> fp32 out -------------
__global__ __launch_bounds__(256) void k_gemm_out(
    const u16* __restrict__ A, const u16* __restrict__ Bt0, float* __restrict__ C){
  __shared__ __attribute__((aligned(16))) u16 sA[128 * 64];
  __shared__ __attribute__((aligned(16))) u16 sB[128 * 64];
  int mt = blockIdx.x, nt = blockIdx.y;
  const u16* Bt = Bt0 + (long)nt * 262144;
  int tid = threadIdx.x;
  int lane = tid & 63, wave = tid >> 6, l15 = lane & 15, quad = lane >> 4;
  int ro = (wave & 1) * 64, co = (wave >> 1) * 64;
  int xm7 = l15 & 7;
  int srow = tid >> 3;
  int gch  = (tid & 7) ^ (srow & 7);
  const u16* Ag = A  + ((long)(mt * 128) + srow) * 2048 + (gch << 3);
  const u16* Bg = Bt + (long)srow * 2048 + (gch << 3);
  u16* lA = sA + tid * 8;
  u16* lB = sB + tid * 8;
  floatx4 acc[4][4];
  const floatx4 fz = {0.f, 0.f, 0.f, 0.f};
  #pragma unroll
  for(int r = 0; r < 4; r++)
    #pragma unroll
    for(int c = 0; c < 4; c++) acc[r][c] = fz;
  for(int k0 = 0; k0 < 2048; k0 += 64){
    #pragma unroll
    for(int r = 0; r < 4; r++){
      gload16(Ag + (long)r * 65536 + k0, lA + r * 2048);
      gload16(Bg + (long)r * 65536 + k0, lB + r * 2048);
    }
    __syncthreads();
    #pragma unroll
    for(int ks = 0; ks < 2; ks++){
      short8 af[4], bfr[4];
      #pragma unroll
      for(int r = 0; r < 4; r++)
        af[r]  = *(const short8*)(sA + ((ro + r * 16 + l15) << 6) + ((((ks << 2) | quad) ^ xm7) << 3));
      #pragma unroll
      for(int c = 0; c < 4; c++)
        bfr[c] = *(const short8*)(sB + ((co + c * 16 + l15) << 6) + ((((ks << 2) | quad) ^ xm7) << 3));
      #pragma unroll
      for(int r = 0; r < 4; r++)
        #pragma unroll
        for(int c = 0; c < 4; c++)
          acc[r][c] = __builtin_amdgcn_mfma_f32_16x16x32_bf16(af[r], bfr[c], acc[r][c], 0, 0, 0);
    }
    __syncthreads();
  }
  long rb0 = (long)mt * 128 + ro + quad * 4;
  #pragma unroll
  for(int r = 0; r < 4; r++)
    #pragma unroll
    for(int c = 0; c < 4; c++){
      int col = nt * 128 + co + c * 16 + l15;
      #pragma unroll
      for(int j = 0; j < 4; j++)
        C[(rb0 + r * 16 + j) * 2048 + col] = acc[r][c][j];
    }
}

// ---- flash attention v3.1 --------------------------------------------------
// Q-tile 64 (4 waves x 16 rows), K-tile 64, causal, fixed-max softmax
// (softcap bounds z to [-50,50] so p=e^z is safe). K/V staged by
// global_load_lds into double-buffered XOR-swizzled LDS; one barrier/tile;
// DMA for tile kt+1 flies during compute of tile kt. Diag/non-diag split.
__global__ __launch_bounds__(256) void k_flash(
    const u16* __restrict__ qb, const u16* __restrict__ kb,
    const u16* __restrict__ vt, u16* __restrict__ enc){
  __shared__ __attribute__((aligned(16))) u16 sK[2 * 64 * 128];   // 32 KB
  __shared__ __attribute__((aligned(16))) u16 sVt[2 * 128 * 64];  // 32 KB
  __shared__ __attribute__((aligned(16))) u16 sP[4][16][72];      // 9 KB
  int qt = 31 - blockIdx.y;                    // longest blocks dispatch first
  int hidx = blockIdx.x;
  int b = hidx >> 4, kv = (hidx >> 1) & 7, g = hidx & 1;
  int tid = threadIdx.x;
  int lane = tid & 63, wave = tid >> 6, l15 = lane & 15, quad = lane >> 4;

  short8 qf[4];
  {
    const u16* qg = qb + ((long)b * 2048 + qt * 64 + wave * 16 + l15) * 2048
                       + (kv * 2 + g) * 128 + quad * 8;
    #pragma unroll
    for(int ks = 0; ks < 4; ks++) qf[ks] = *(const short8*)(qg + ks * 32);
  }

  int krow = tid >> 4;
  int kch  = (tid & 15) ^ krow;
  const u16* Kg = kb + ((long)b * 2048 + krow) * 1024 + kv * 128 + (kch << 3);
  int vrow = tid >> 3;
  int vch  = (tid & 7) ^ (vrow & 7);
  const u16* Vg = vt + ((long)(b * 8 + kv) * 128 + vrow) * 2048 + (vch << 3);
  u16* lK = sK  + tid * 8;
  u16* lV = sVt + tid * 8;
  #pragma unroll
  for(int r = 0; r < 4; r++){                   // preload tile 0 -> buf 0
    gload16(Kg + (long)r * 16384, lK + r * 2048);
    gload16(Vg + (long)r * 65536, lV + r * 2048);
  }

  float l_loc[4] = {0.f, 0.f, 0.f, 0.f};
  floatx4 o_acc[8];
  const floatx4 fz = {0.f, 0.f, 0.f, 0.f};
  #pragma unroll
  for(int c = 0; c < 8; c++) o_acc[c] = fz;

  const float c1 = 0.057707801635558536f;      // 2*log2(e)/50
  const float c2 = -144.26950408889634f;       // -100*log2(e)
  const float c3 = 72.13475204444817f;         // 50*log2(e)

  for(int kt = 0; kt <= qt; kt++){
    int buf = (kt & 1) * 8192;
    __syncthreads();                           // drains DMAs for this buf + frees other buf
    if(kt < qt){                               // async stage tile kt+1 into other buf
      int nb = buf ^ 8192;
      #pragma unroll
      for(int r = 0; r < 4; r++){
        gload16(Kg + (long)(kt + 1) * 65536 + (long)r * 16384, lK + nb + r * 2048);
        gload16(Vg + (kt + 1) * 64 + (long)r * 65536, lV + nb + r * 2048);
      }
    }
    // S = Q K^T
    floatx4 s_acc[4];
    #pragma unroll
    for(int c = 0; c < 4; c++) s_acc[c] = fz;
    #pragma unroll
    for(int ks = 0; ks < 4; ks++){
      #pragma unroll
      for(int cb = 0; cb < 4; cb++){
        short8 bk = *(const short8*)(sK + buf + ((cb * 16 + l15) << 7)
                                     + ((((ks << 2) | quad) ^ l15) << 3));
        s_acc[cb] = __builtin_amdgcn_mfma_f32_16x16x32_bf16(qf[ks], bk, s_acc[cb], 0, 0, 0);
      }
    }
    // p = exp(50*tanh(s/50)) = exp2(c2/(u+1) + c3), u = exp2(c1*s)
    if(kt < qt){                               // off-diagonal: no mask
      #pragma unroll
      for(int r = 0; r < 4; r++){
        #pragma unroll
        for(int cb = 0; cb < 4; cb++){
          float s = s_acc[cb][r];
          float u = __builtin_amdgcn_exp2f(c1 * s);
          float d = __builtin_amdgcn_rcpf(u + 1.f);
          float p = __builtin_amdgcn_exp2f(__builtin_fmaf(c2, d, c3));
          l_loc[r] += p;
          sP[wave][quad * 4 + r][cb * 16 + l15] = f2b(p);
        }
      }
    } else {                                   // diagonal tile: causal mask
      int rloc = wave * 16 + quad * 4;
      #pragma unroll
      for(int r = 0; r < 4; r++){
        #pragma unroll
        for(int cb = 0; cb < 4; cb++){
          float s = s_acc[cb][r];
          float u = __builtin_amdgcn_exp2f(c1 * s);
          float d = __builtin_amdgcn_rcpf(u + 1.f);
          float p = __builtin_amdgcn_exp2f(__builtin_fmaf(c2, d, c3));
          if(cb * 16 + l15 > rloc + r) p = 0.f;
          l_loc[r] += p;
          sP[wave][quad * 4 + r][cb * 16 + l15] = f2b(p);
        }
      }
    }
    // O += P V
    #pragma unroll
    for(int ks2 = 0; ks2 < 2; ks2++){
      short8 ap = *(const short8*)&sP[wave][l15][ks2 * 32 + quad * 8];
      #pragma unroll
      for(int c = 0; c < 8; c++){
        short8 bv = *(const short8*)(sVt + buf + ((c * 16 + l15) << 6)
                                     + ((((ks2 << 2) | quad) ^ (l15 & 7)) << 3));
        o_acc[c] = __builtin_amdgcn_mfma_f32_16x16x32_bf16(ap, bv, o_acc[c], 0, 0, 0);
      }
    }
  }
  #pragma unroll
  for(int r = 0; r < 4; r++){
    float l = l_loc[r];
    #pragma unroll
    for(int off = 1; off < 16; off <<= 1) l += __shfl_xor(l, off);
    float invl = 1.f / l;
    long rowe = (long)b * 2048 + qt * 64 + wave * 16 + quad * 4 + r;
    #pragma unroll
    for(int c = 0; c < 8; c++)
      enc[rowe * 2048 + (kv * 2 + g) * 128 + c * 16 + l15] = f2b(o_acc[c][r] * invl);
  }
}

// ---------------------------------------------------------------------------
extern "C" void kernel_launch(void* const* d_in, const int* in_sizes, int n_in,
                              void* d_out, int out_size, void* d_ws, size_t ws_size,
                              hipStream_t stream){
  const float* x     = (const float*)d_in[0];
  const int*   posi  = (const int*)  d_in[1];
  // d_in[2] = attn_mask (causal, known analytically) -- unused
  const float* w_q   = (const float*)d_in[3];
  const float* w_kv  = (const float*)d_in[4];
  const float* w_out = (const float*)d_in[5];
  float* out = (float*)d_out;

  char* w = (char*)d_ws;                        // 78 MB used
  u16* xb     = (u16*)(w);                      // 16 MB (reused as enc after qkv)
  u16* wq_t   = (u16*)(w + 16777216);           //  8 MB [16][128][2048]
  u16* wkv_t  = (u16*)(w + 25165824);           //  8 MB [2][8][128][2048]
  u16* wout_t = (u16*)(w + 33554432);           //  8 MB [2048][2048]
  u16* q_buf  = (u16*)(w + 41943040);           // 16 MB [4096][2048]
  u16* k_buf  = (u16*)(w + 58720256);           //  8 MB [4096][1024]
  u16* v_t    = (u16*)(w + 67108864);           //  8 MB [2][8][128][2048]
  float* tab  = (float*)(w + 75497472);         //  2 MB sin/cos
  u16* enc    = xb;                             // xb dead after qkv

  k_prep    <<<12288, 256, 0, stream>>>(x, xb, w_q, wq_t, w_kv, wkv_t, w_out, wout_t, posi, tab);
  k_gemm_qkv<<<dim3(16, 16), 512, 0, stream>>>(xb, wq_t, wkv_t, tab, q_buf, k_buf, v_t);
  k_flash   <<<dim3(32, 32), 256, 0, stream>>>(q_buf, k_buf, v_t, enc);
  k_gemm_out<<<dim3(32, 16), 256, 0, stream>>>(enc, wout_t, out);
}

// Round 3
// 322.962 us; speedup vs baseline: 1.0616x; 1.0092x over previous
//
#include <hip/hip_runtime.h>

// ---------------------------------------------------------------------------
// Attention (GQA + RoPE + softcap + causal) on gfx950, bf16 MFMA pipeline.
// B=2 T=2048 D=2048, NH=16 NKV=8 HD=128, softcap=50, causal.
// R7 (= R6 resubmit after infra failure): k_gemm_qkv inner loop in the
// verified m201 8-phase form: phase = C-quadrant x full K=64 (16 MFMA),
// register reuse across phases (12/8/4/8 ds_reads), plain s_barrier + bare
// lgkmcnt(0) + setprio, NO sched_barrier in the loop (compiler interleaves
// reads/stages with MFMA). 10-slot ring + vmcnt(4)/K-tile checkpoint kept
// (WAR >=2 barriers).
// ---------------------------------------------------------------------------

typedef unsigned short u16;
typedef __attribute__((ext_vector_type(8))) short short8;   // 8 x bf16 (4 VGPRs)
typedef __attribute__((ext_vector_type(4))) float floatx4;  // MFMA acc

static __device__ __forceinline__ u16 f2b(float f){
  unsigned u = __float_as_uint(f);
  u = (u + 0x7fffu + ((u >> 16) & 1u)) >> 16;   // RNE
  return (u16)u;
}
static __device__ __forceinline__ float b2f(u16 u){
  return __uint_as_float(((unsigned)u) << 16);
}
// async global->LDS DMA, 16B per lane; LDS dest = wave-uniform base + lane*16
static __device__ __forceinline__ void gload16(const u16* g, u16* l){
  __builtin_amdgcn_global_load_lds(
      (const __attribute__((address_space(1))) unsigned int*)g,
      (__attribute__((address_space(3))) unsigned int*)l, 16, 0, 0);
}

// ---- prep: x->bf16 | w_q/w_kv/w_out transpose->B^T bf16 | sin/cos table ----
static __device__ void tr64(const float* __restrict__ s, u16* __restrict__ d,
                            int sRS, int dRS, float (*t)[65], int tid){
  #pragma unroll
  for(int i = 0; i < 16; i++){
    int idx = tid + 256 * i;
    t[idx >> 6][idx & 63] = s[(long)(idx >> 6) * sRS + (idx & 63)];
  }
  __syncthreads();
  #pragma unroll
  for(int i = 0; i < 16; i++){
    int idx = tid + 256 * i;
    d[(long)(idx >> 6) * dRS + (idx & 63)] = f2b(t[idx & 63][idx >> 6]);
  }
}

__global__ __launch_bounds__(256) void k_prep(
    const float* __restrict__ x, u16* __restrict__ xb,
    const float* __restrict__ wq, u16* __restrict__ wq_t,
    const float* __restrict__ wkv, u16* __restrict__ wkv_t,
    const float* __restrict__ wo, u16* __restrict__ wo_t,
    const int* __restrict__ pos, float* __restrict__ tab){
  __shared__ float t[64][65];
  int blk = blockIdx.x, tid = threadIdx.x;
  if(blk < 8192){                               // x fp32 -> bf16
    int i = blk * 256 + tid;
    float4 v = ((const float4*)x)[i];
    ushort4 o = make_ushort4(f2b(v.x), f2b(v.y), f2b(v.z), f2b(v.w));
    ((ushort4*)xb)[i] = o;
  } else if(blk < 9216){                        // w_q [16][2048][128] -> [16][128][2048]
    int q = blk - 8192;
    int bx = q & 1, by = (q >> 1) & 31, bz = q >> 6;
    tr64(wq + (long)bz * 262144 + (long)by * 64 * 128 + bx * 64,
         wq_t + (long)bz * 262144 + (long)bx * 64 * 2048 + by * 64, 128, 2048, t, tid);
  } else if(blk < 10240){                       // w_kv [16][2048][128] -> [16][128][2048]
    int q = blk - 9216;
    int bx = q & 1, by = (q >> 1) & 31, bz = q >> 6;
    tr64(wkv + (long)bz * 262144 + (long)by * 64 * 128 + bx * 64,
         wkv_t + (long)bz * 262144 + (long)bx * 64 * 2048 + by * 64, 128, 2048, t, tid);
  } else if(blk < 11264){                       // w_out [2048][2048] -> transpose
    int q = blk - 10240;
    int bx = q & 31, by = q >> 5;
    tr64(wo + (long)by * 64 * 2048 + bx * 64,
         wo_t + (long)bx * 64 * 2048 + by * 64, 2048, 2048, t, tid);
  } else {                                      // sin/cos: tab[row][0:64]=sin, [64:128]=cos
    int idx = (blk - 11264) * 256 + tid;        // 262,144 = 4096 rows x 64 h
    int row = idx >> 6, h = idx & 63;
    float pf = (float)pos[row];
    float inv = exp2f(-0.20762050593045077f * (float)h);  // 10000^(-h/64)
    float ang = pf * inv;
    tab[(row << 7) + h]      = sinf(ang);
    tab[(row << 7) + 64 + h] = cosf(ang);
  }
}

// ---- fused QKV projection GEMM + RoPE + V-transpose epilogue ---------------
// 256x256 tile, BK=64, 512 threads = 8 waves (2M x 4N), each wave owns a
// 128x64 output sub-tile (acc[8][4]). 4 phases per K-tile, each phase = one
// C-quadrant x full K=64: (m0,n01)(m1,n01)(m1,n23)(m0,n23). B-frags are held
// in registers 2 phases; A m-half frags re-read once. Per phase: ds_reads
// (12/8/4/8), 1 half-tile stage (16KB via global_load_lds), s_barrier,
// lgkmcnt(0), setprio(1), 16 MFMA, setprio(0), s_barrier. Staging goes
// through a 10-slot half-tile ring (160 KiB): half i issued at phase i,
// tile t computed at phases 4t+6..4t+9; vmcnt(4) once per K-tile (p3) =>
// tile t+1 fully landed; slot overwrite always >=2 barriers after last read.
// nt<8 -> q heads 2nt,2nt+1 ; 8..11 -> k ; 12..15 -> v (transposed).
#define STAGE_A(tt, h) do{ \
  const u16* s_ = Ag + (tt) * 64 + (h) * 262144; \
  u16* d_ = ld + ss * 8192; \
  gload16(s_, d_); gload16(s_ + 131072, d_ + 4096); \
  ss++; if(ss == 10) ss = 0; }while(0)
#define STAGE_B(tt, h) do{ \
  const u16* s_ = Bg + (tt) * 64 + (h) * 262144; \
  u16* d_ = ld + ss * 8192; \
  gload16(s_, d_); gload16(s_ + 131072, d_ + 4096); \
  ss++; if(ss == 10) ss = 0; }while(0)

__global__ __launch_bounds__(512, 2) void k_gemm_qkv(
    const u16* __restrict__ A, const u16* __restrict__ wq_t, const u16* __restrict__ wkv_t,
    const float* __restrict__ tab,
    u16* __restrict__ qb, u16* __restrict__ kb, u16* __restrict__ vtp){
  __shared__ __attribute__((aligned(16))) u16 ring[81920];  // 10 x 16KB = 160 KiB
  int mt = blockIdx.x, nt = blockIdx.y;
  const u16* Bt = (nt < 8) ? (wq_t + (long)nt * 524288)
                           : (wkv_t + (long)(nt - 8) * 524288);
  int tid = threadIdx.x;
  int lane = tid & 63, wave = tid >> 6, l15 = lane & 15, quad = lane >> 4;
  int wr = wave >> 2, wc = wave & 3;            // 2M x 4N wave grid
  int cq0 = quad ^ (l15 & 7), cq1 = cq0 ^ 4;    // swizzled chunk, ks=0 / ks=1
  int srow = tid >> 3;
  int gch  = (tid & 7) ^ (srow & 7);            // XOR-swizzled staging chunks
  const u16* Ag = A  + ((long)mt * 256 + srow) * 2048 + (gch << 3);
  const u16* Bg = Bt + (long)srow * 2048 + (gch << 3);
  u16* ld = ring + tid * 8;
  int aB = l15 << 6;                            // in-slot elem offsets
  int bB = ((wc & 1) * 64 + l15) << 6;
  int sa = wr;                                  // A-slot for tile t: (4t+wr)%10
  int sb = 2 + (wc >> 1);                       // B-slot: (4t+2+(wc>>1))%10
  int ss = 0;                                   // stage slot: phase % 10
  floatx4 acc[8][4];
  const floatx4 fz = {0.f, 0.f, 0.f, 0.f};
  #pragma unroll
  for(int m = 0; m < 8; m++)
    #pragma unroll
    for(int n = 0; n < 4; n++) acc[m][n] = fz;

  // prologue: halves 0..5 = A0(0) A1(0) B0(0) B1(0) A0(1) A1(1)
  STAGE_A(0, 0); STAGE_A(0, 1); STAGE_B(0, 0); STAGE_B(0, 1);
  STAGE_A(1, 0); STAGE_A(1, 1);
  asm volatile("s_waitcnt vmcnt(4)" ::: "memory");  // tile 0 landed
  __builtin_amdgcn_s_barrier();

  #pragma unroll 1
  for(int t = 0; t < 32; t++){
    const u16* aS = ring + sa * 8192;
    const u16* bS = ring + sb * 8192;
    int tB = (t < 31) ? t + 1 : 31;             // clamped tail = dummy re-reads
    int tA = (t < 30) ? t + 2 : 31;
    short8 a0[4], a1[4], b0[2], b1[2];
    // ---- p0: quadrant (m0, n0..1), full K=64 — 12 ds_reads ----------------
    #pragma unroll
    for(int n = 0; n < 2; n++){
      b0[n] = *(const short8*)(bS + bB + (n << 10) + (cq0 << 3));
      b1[n] = *(const short8*)(bS + bB + (n << 10) + (cq1 << 3));
    }
    #pragma unroll
    for(int m = 0; m < 4; m++){
      a0[m] = *(const short8*)(aS + aB + (m << 10) + (cq0 << 3));
      a1[m] = *(const short8*)(aS + aB + (m << 10) + (cq1 << 3));
    }
    STAGE_B(tB, 0);
    __builtin_amdgcn_s_barrier();
    asm volatile("s_waitcnt lgkmcnt(0)");
    __builtin_amdgcn_s_setprio(1);
    #pragma unroll
    for(int m = 0; m < 4; m++)
      #pragma unroll
      for(int n = 0; n < 2; n++)
        acc[m][n] = __builtin_amdgcn_mfma_f32_16x16x32_bf16(a0[m], b0[n], acc[m][n], 0, 0, 0);
    #pragma unroll
    for(int m = 0; m < 4; m++)
      #pragma unroll
      for(int n = 0; n < 2; n++)
        acc[m][n] = __builtin_amdgcn_mfma_f32_16x16x32_bf16(a1[m], b1[n], acc[m][n], 0, 0, 0);
    __builtin_amdgcn_s_setprio(0);
    __builtin_amdgcn_s_barrier();
    // ---- p1: quadrant (m1, n0..1) — 8 ds_reads (A m1), reuse b ------------
    #pragma unroll
    for(int m = 0; m < 4; m++){
      a0[m] = *(const short8*)(aS + aB + 4096 + (m << 10) + (cq0 << 3));
      a1[m] = *(const short8*)(aS + aB + 4096 + (m << 10) + (cq1 << 3));
    }
    STAGE_B(tB, 1);
    __builtin_amdgcn_s_barrier();
    asm volatile("s_waitcnt lgkmcnt(0)");
    __builtin_amdgcn_s_setprio(1);
    #pragma unroll
    for(int m = 0; m < 4; m++)
      #pragma unroll
      for(int n = 0; n < 2; n++)
        acc[4 + m][n] = __builtin_amdgcn_mfma_f32_16x16x32_bf16(a0[m], b0[n], acc[4 + m][n], 0, 0, 0);
    #pragma unroll
    for(int m = 0; m < 4; m++)
      #pragma unroll
      for(int n = 0; n < 2; n++)
        acc[4 + m][n] = __builtin_amdgcn_mfma_f32_16x16x32_bf16(a1[m], b1[n], acc[4 + m][n], 0, 0, 0);
    __builtin_amdgcn_s_setprio(0);
    __builtin_amdgcn_s_barrier();
    // ---- p2: quadrant (m1, n2..3) — 4 ds_reads (B n23), reuse a -----------
    #pragma unroll
    for(int n = 0; n < 2; n++){
      b0[n] = *(const short8*)(bS + bB + ((2 + n) << 10) + (cq0 << 3));
      b1[n] = *(const short8*)(bS + bB + ((2 + n) << 10) + (cq1 << 3));
    }
    STAGE_A(tA, 0);
    __builtin_amdgcn_s_barrier();
    asm volatile("s_waitcnt lgkmcnt(0)");
    __builtin_amdgcn_s_setprio(1);
    #pragma unroll
    for(int m = 0; m < 4; m++)
      #pragma unroll
      for(int n = 0; n < 2; n++)
        acc[4 + m][2 + n] = __builtin_amdgcn_mfma_f32_16x16x32_bf16(a0[m], b0[n], acc[4 + m][2 + n], 0, 0, 0);
    #pragma unroll
    for(int m = 0; m < 4; m++)
      #pragma unroll
      for(int n = 0; n < 2; n++)
        acc[4 + m][2 + n] = __builtin_amdgcn_mfma_f32_16x16x32_bf16(a1[m], b1[n], acc[4 + m][2 + n], 0, 0, 0);
    __builtin_amdgcn_s_setprio(0);
    __builtin_amdgcn_s_barrier();
    // ---- p3: quadrant (m0, n2..3) — 8 ds_reads (A m0 again), reuse b ------
    #pragma unroll
    for(int m = 0; m < 4; m++){
      a0[m] = *(const short8*)(aS + aB + (m << 10) + (cq0 << 3));
      a1[m] = *(const short8*)(aS + aB + (m << 10) + (cq1 << 3));
    }
    STAGE_A(tA, 1);
    asm volatile("s_waitcnt vmcnt(4)" ::: "memory");  // tile t+1 fully landed
    __builtin_amdgcn_s_barrier();
    asm volatile("s_waitcnt lgkmcnt(0)");
    __builtin_amdgcn_s_setprio(1);
    #pragma unroll
    for(int m = 0; m < 4; m++)
      #pragma unroll
      for(int n = 0; n < 2; n++)
        acc[m][2 + n] = __builtin_amdgcn_mfma_f32_16x16x32_bf16(a0[m], b0[n], acc[m][2 + n], 0, 0, 0);
    #pragma unroll
    for(int m = 0; m < 4; m++)
      #pragma unroll
      for(int n = 0; n < 2; n++)
        acc[m][2 + n] = __builtin_amdgcn_mfma_f32_16x16x32_bf16(a1[m], b1[n], acc[m][2 + n], 0, 0, 0);
    __builtin_amdgcn_s_setprio(0);
    __builtin_amdgcn_s_barrier();
    sa += 4; if(sa >= 10) sa -= 10;
    sb += 4; if(sb >= 10) sb -= 10;
  }

  // ---- epilogue: drain DMAs, reuse ring as sT[256][132], rope/v-transpose
  asm volatile("s_waitcnt vmcnt(0)" ::: "memory");
  __syncthreads();
  u16* sT = ring;
  int grow0 = mt * 256;
  int hb = wc >> 1, wcl = wc & 1;
  #pragma unroll 1
  for(int hh = 0; hh < 2; hh++){                // two heads per 256-wide tile
    if(hb == hh){                               // stash this head's columns
      #pragma unroll
      for(int m = 0; m < 8; m++){
        int row = wr * 128 + m * 16 + quad * 4;
        #pragma unroll
        for(int n = 0; n < 4; n++){
          int colh = wcl * 64 + n * 16 + l15;
          #pragma unroll
          for(int j = 0; j < 4; j++)
            sT[(row + j) * 132 + colh] = f2b(acc[m][n][j]);
        }
      }
    }
    __syncthreads();
    if(nt < 12){                                // q or k: rope(+scale)
      float scale = (nt < 8) ? 0.08838834764831845f : 1.0f;
      u16* dst = (nt < 8) ? qb : kb;
      int dS   = (nt < 8) ? 2048 : 1024;
      int dcol = (nt < 8) ? (nt * 2 + hh) * 128 : ((nt - 8) * 2 + hh) * 128;
      #pragma unroll
      for(int it = 0; it < 16; it++){
        int idx = tid + 512 * it;               // 8192 u32 pair-words
        int row = idx >> 5, cw = idx & 31;
        int grow = grow0 + row;
        unsigned lo = *(const unsigned*)&sT[row * 132 + 2 * cw];
        unsigned hi = *(const unsigned*)&sT[row * 132 + 64 + 2 * cw];
        float2 sn = *(const float2*)&tab[(grow << 7) + 2 * cw];
        float2 cs = *(const float2*)&tab[(grow << 7) + 64 + 2 * cw];
        float x1a = b2f((u16)lo), x1b = b2f((u16)(lo >> 16));
        float x2a = b2f((u16)hi), x2b = b2f((u16)(hi >> 16));
        float o1a = (x1a * cs.x - x2a * sn.x) * scale;
        float o1b = (x1b * cs.y - x2b * sn.y) * scale;
        float o2a = (x2a * cs.x + x1a * sn.x) * scale;
        float o2b = (x2b * cs.y + x1b * sn.y) * scale;
        unsigned w1 = (unsigned)f2b(o1a) | ((unsigned)f2b(o1b) << 16);
        unsigned w2 = (unsigned)f2b(o2a) | ((unsigned)f2b(o2b) << 16);
        *(unsigned*)&dst[(long)grow * dS + dcol + 2 * cw] = w1;
        *(unsigned*)&dst[(long)grow * dS + dcol + 64 + 2 * cw] = w2;
      }
    } else {                                    // v: transposed -> v_t[b][kv][h][s]
      int b = mt >> 3, kvh = (nt - 12) * 2 + hh;
      u16* vt = vtp + (long)(b * 8 + kvh) * 262144;
      int tcol0 = (mt & 7) * 256;
      int h = tid >> 2, s0 = (tid & 3) * 64;
      #pragma unroll
      for(int i = 0; i < 16; i++){
        int s = s0 + i * 4;
        ushort4 v4 = make_ushort4(sT[(s    ) * 132 + h], sT[(s + 1) * 132 + h],
                                  sT[(s + 2) * 132 + h], sT[(s + 3) * 132 + h]);
        *(ushort4*)&vt[(long)h * 2048 + tcol0 + s] = v4;
      }
    }
    __syncthreads();
  }
}
#undef STAGE_A
#undef STAGE_B

// ---- out projection GEMM: enc[4096x2048] x w_out^T -> fp32 out -------------
__global__ __launch_bounds__(256) void k_gemm_out(
    const u16* __restrict__ A, const u16* __restrict__ Bt0, float* __restrict__ C){
  __shared__ __attribute__((aligned(16))) u16 sA[128 * 64];
  __shared__ __attribute__((aligned(16))) u16 sB[128 * 64];
  int mt = blockIdx.x, nt = blockIdx.y;
  const u16* Bt = Bt0 + (long)nt * 262144;
  int tid = threadIdx.x;
  int lane = tid & 63, wave = tid >> 6, l15 = lane & 15, quad = lane >> 4;
  int ro = (wave & 1) * 64, co = (wave >> 1) * 64;
  int xm7 = l15 & 7;
  int srow = tid >> 3;
  int gch  = (tid & 7) ^ (srow & 7);
  const u16* Ag = A  + ((long)(mt * 128) + srow) * 2048 + (gch << 3);
  const u16* Bg = Bt + (long)srow * 2048 + (gch << 3);
  u16* lA = sA + tid * 8;
  u16* lB = sB + tid * 8;
  floatx4 acc[4][4];
  const floatx4 fz = {0.f, 0.f, 0.f, 0.f};
  #pragma unroll
  for(int r = 0; r < 4; r++)
    #pragma unroll
    for(int c = 0; c < 4; c++) acc[r][c] = fz;
  for(int k0 = 0; k0 < 2048; k0 += 64){
    #pragma unroll
    for(int r = 0; r < 4; r++){
      gload16(Ag + (long)r * 65536 + k0, lA + r * 2048);
      gload16(Bg + (long)r * 65536 + k0, lB + r * 2048);
    }
    __syncthreads();
    #pragma unroll
    for(int ks = 0; ks < 2; ks++){
      short8 af[4], bfr[4];
      #pragma unroll
      for(int r = 0; r < 4; r++)
        af[r]  = *(const short8*)(sA + ((ro + r * 16 + l15) << 6) + ((((ks << 2) | quad) ^ xm7) << 3));
      #pragma unroll
      for(int c = 0; c < 4; c++)
        bfr[c] = *(const short8*)(sB + ((co + c * 16 + l15) << 6) + ((((ks << 2) | quad) ^ xm7) << 3));
      #pragma unroll
      for(int r = 0; r < 4; r++)
        #pragma unroll
        for(int c = 0; c < 4; c++)
          acc[r][c] = __builtin_amdgcn_mfma_f32_16x16x32_bf16(af[r], bfr[c], acc[r][c], 0, 0, 0);
    }
    __syncthreads();
  }
  long rb0 = (long)mt * 128 + ro + quad * 4;
  #pragma unroll
  for(int r = 0; r < 4; r++)
    #pragma unroll
    for(int c = 0; c < 4; c++){
      int col = nt * 128 + co + c * 16 + l15;
      #pragma unroll
      for(int j = 0; j < 4; j++)
        C[(rb0 + r * 16 + j) * 2048 + col] = acc[r][c][j];
    }
}

// ---- flash attention v3.1 --------------------------------------------------
// Q-tile 64 (4 waves x 16 rows), K-tile 64, causal, fixed-max softmax
// (softcap bounds z to [-50,50] so p=e^z is safe). K/V staged by
// global_load_lds into double-buffered XOR-swizzled LDS; one barrier/tile;
// DMA for tile kt+1 flies during compute of tile kt. Diag/non-diag split.
__global__ __launch_bounds__(256) void k_flash(
    const u16* __restrict__ qb, const u16* __restrict__ kb,
    const u16* __restrict__ vt, u16* __restrict__ enc){
  __shared__ __attribute__((aligned(16))) u16 sK[2 * 64 * 128];   // 32 KB
  __shared__ __attribute__((aligned(16))) u16 sVt[2 * 128 * 64];  // 32 KB
  __shared__ __attribute__((aligned(16))) u16 sP[4][16][72];      // 9 KB
  int qt = 31 - blockIdx.y;                    // longest blocks dispatch first
  int hidx = blockIdx.x;
  int b = hidx >> 4, kv = (hidx >> 1) & 7, g = hidx & 1;
  int tid = threadIdx.x;
  int lane = tid & 63, wave = tid >> 6, l15 = lane & 15, quad = lane >> 4;

  short8 qf[4];
  {
    const u16* qg = qb + ((long)b * 2048 + qt * 64 + wave * 16 + l15) * 2048
                       + (kv * 2 + g) * 128 + quad * 8;
    #pragma unroll
    for(int ks = 0; ks < 4; ks++) qf[ks] = *(const short8*)(qg + ks * 32);
  }

  int krow = tid >> 4;
  int kch  = (tid & 15) ^ krow;
  const u16* Kg = kb + ((long)b * 2048 + krow) * 1024 + kv * 128 + (kch << 3);
  int vrow = tid >> 3;
  int vch  = (tid & 7) ^ (vrow & 7);
  const u16* Vg = vt + ((long)(b * 8 + kv) * 128 + vrow) * 2048 + (vch << 3);
  u16* lK = sK  + tid * 8;
  u16* lV = sVt + tid * 8;
  #pragma unroll
  for(int r = 0; r < 4; r++){                   // preload tile 0 -> buf 0
    gload16(Kg + (long)r * 16384, lK + r * 2048);
    gload16(Vg + (long)r * 65536, lV + r * 2048);
  }

  float l_loc[4] = {0.f, 0.f, 0.f, 0.f};
  floatx4 o_acc[8];
  const floatx4 fz = {0.f, 0.f, 0.f, 0.f};
  #pragma unroll
  for(int c = 0; c < 8; c++) o_acc[c] = fz;

  const float c1 = 0.057707801635558536f;      // 2*log2(e)/50
  const float c2 = -144.26950408889634f;       // -100*log2(e)
  const float c3 = 72.13475204444817f;         // 50*log2(e)

  for(int kt = 0; kt <= qt; kt++){
    int buf = (kt & 1) * 8192;
    __syncthreads();                           // drains DMAs for this buf + frees other buf
    if(kt < qt){                               // async stage tile kt+1 into other buf
      int nb = buf ^ 8192;
      #pragma unroll
      for(int r = 0; r < 4; r++){
        gload16(Kg + (long)(kt + 1) * 65536 + (long)r * 16384, lK + nb + r * 2048);
        gload16(Vg + (kt + 1) * 64 + (long)r * 65536, lV + nb + r * 2048);
      }
    }
    // S = Q K^T
    floatx4 s_acc[4];
    #pragma unroll
    for(int c = 0; c < 4; c++) s_acc[c] = fz;
    #pragma unroll
    for(int ks = 0; ks < 4; ks++){
      #pragma unroll
      for(int cb = 0; cb < 4; cb++){
        short8 bk = *(const short8*)(sK + buf + ((cb * 16 + l15) << 7)
                                     + ((((ks << 2) | quad) ^ l15) << 3));
        s_acc[cb] = __builtin_amdgcn_mfma_f32_16x16x32_bf16(qf[ks], bk, s_acc[cb], 0, 0, 0);
      }
    }
    // p = exp(50*tanh(s/50)) = exp2(c2/(u+1) + c3), u = exp2(c1*s)
    if(kt < qt){                               // off-diagonal: no mask
      #pragma unroll
      for(int r = 0; r < 4; r++){
        #pragma unroll
        for(int cb = 0; cb < 4; cb++){
          float s = s_acc[cb][r];
          float u = __builtin_amdgcn_exp2f(c1 * s);
          float d = __builtin_amdgcn_rcpf(u + 1.f);
          float p = __builtin_amdgcn_exp2f(__builtin_fmaf(c2, d, c3));
          l_loc[r] += p;
          sP[wave][quad * 4 + r][cb * 16 + l15] = f2b(p);
        }
      }
    } else {                                   // diagonal tile: causal mask
      int rloc = wave * 16 + quad * 4;
      #pragma unroll
      for(int r = 0; r < 4; r++){
        #pragma unroll
        for(int cb = 0; cb < 4; cb++){
          float s = s_acc[cb][r];
          float u = __builtin_amdgcn_exp2f(c1 * s);
          float d = __builtin_amdgcn_rcpf(u + 1.f);
          float p = __builtin_amdgcn_exp2f(__builtin_fmaf(c2, d, c3));
          if(cb * 16 + l15 > rloc + r) p = 0.f;
          l_loc[r] += p;
          sP[wave][quad * 4 + r][cb * 16 + l15] = f2b(p);
        }
      }
    }
    // O += P V
    #pragma unroll
    for(int ks2 = 0; ks2 < 2; ks2++){
      short8 ap = *(const short8*)&sP[wave][l15][ks2 * 32 + quad * 8];
      #pragma unroll
      for(int c = 0; c < 8; c++){
        short8 bv = *(const short8*)(sVt + buf + ((c * 16 + l15) << 6)
                                     + ((((ks2 << 2) | quad) ^ (l15 & 7)) << 3));
        o_acc[c] = __builtin_amdgcn_mfma_f32_16x16x32_bf16(ap, bv, o_acc[c], 0, 0, 0);
      }
    }
  }
  #pragma unroll
  for(int r = 0; r < 4; r++){
    float l = l_loc[r];
    #pragma unroll
    for(int off = 1; off < 16; off <<= 1) l += __shfl_xor(l, off);
    float invl = 1.f / l;
    long rowe = (long)b * 2048 + qt * 64 + wave * 16 + quad * 4 + r;
    #pragma unroll
    for(int c = 0; c < 8; c++)
      enc[rowe * 2048 + (kv * 2 + g) * 128 + c * 16 + l15] = f2b(o_acc[c][r] * invl);
  }
}

// ---------------------------------------------------------------------------
extern "C" void kernel_launch(void* const* d_in, const int* in_sizes, int n_in,
                              void* d_out, int out_size, void* d_ws, size_t ws_size,
                              hipStream_t stream){
  const float* x     = (const float*)d_in[0];
  const int*   posi  = (const int*)  d_in[1];
  // d_in[2] = attn_mask (causal, known analytically) -- unused
  const float* w_q   = (const float*)d_in[3];
  const float* w_kv  = (const float*)d_in[4];
  const float* w_out = (const float*)d_in[5];
  float* out = (float*)d_out;

  char* w = (char*)d_ws;                        // 78 MB used
  u16* xb     = (u16*)(w);                      // 16 MB (reused as enc after qkv)
  u16* wq_t   = (u16*)(w + 16777216);           //  8 MB [16][128][2048]
  u16* wkv_t  = (u16*)(w + 25165824);           //  8 MB [2][8][128][2048]
  u16* wout_t = (u16*)(w + 33554432);           //  8 MB [2048][2048]
  u16* q_buf  = (u16*)(w + 41943040);           // 16 MB [4096][2048]
  u16* k_buf  = (u16*)(w + 58720256);           //  8 MB [4096][1024]
  u16* v_t    = (u16*)(w + 67108864);           //  8 MB [2][8][128][2048]
  float* tab  = (float*)(w + 75497472);         //  2 MB sin/cos
  u16* enc    = xb;                             // xb dead after qkv

  k_prep    <<<12288, 256, 0, stream>>>(x, xb, w_q, wq_t, w_kv, wkv_t, w_out, wout_t, posi, tab);
  k_gemm_qkv<<<dim3(16, 16), 512, 0, stream>>>(xb, wq_t, wkv_t, tab, q_buf, k_buf, v_t);
  k_flash   <<<dim3(32, 32), 256, 0, stream>>>(q_buf, k_buf, v_t, enc);
  k_gemm_out<<<dim3(32, 16), 256, 0, stream>>>(enc, wout_t, out);
}

// Round 4
// 320.845 us; speedup vs baseline: 1.0686x; 1.0066x over previous
//
#include <hip/hip_runtime.h>

// ---------------------------------------------------------------------------
// Attention (GQA + RoPE + softcap + causal) on gfx950, bf16 MFMA pipeline.
// B=2 T=2048 D=2048, NH=16 NKV=8 HD=128, softcap=50, causal.
// R8: k_gemm_qkv hybrid staging. A: 12-slot x 8KB quarter-tile DMA ring
//     (96 KiB), staged 2 tiles ahead (4-8 phase landing slack), vmcnt(8)
//     checkpoint once per K-tile. B: register-staged double buffer (2x32KiB,
//     total LDS 160 KiB): dwordx4 loads issued 2 tiles early, ds_write 1 tile
//     early (compiler-managed waits), halving DMA-engine bytes. Bijective
//     XCD swizzle (4mt x 8nt rectangle per XCD) for L2-local panel reads.
// ---------------------------------------------------------------------------

typedef unsigned short u16;
typedef __attribute__((ext_vector_type(8))) short short8;   // 8 x bf16 (4 VGPRs)
typedef __attribute__((ext_vector_type(4))) float floatx4;  // MFMA acc

static __device__ __forceinline__ u16 f2b(float f){
  unsigned u = __float_as_uint(f);
  u = (u + 0x7fffu + ((u >> 16) & 1u)) >> 16;   // RNE
  return (u16)u;
}
static __device__ __forceinline__ float b2f(u16 u){
  return __uint_as_float(((unsigned)u) << 16);
}
// async global->LDS DMA, 16B per lane; LDS dest = wave-uniform base + lane*16
static __device__ __forceinline__ void gload16(const u16* g, u16* l){
  __builtin_amdgcn_global_load_lds(
      (const __attribute__((address_space(1))) unsigned int*)g,
      (__attribute__((address_space(3))) unsigned int*)l, 16, 0, 0);
}

// ---- prep: x->bf16 | w_q/w_kv/w_out transpose->B^T bf16 | sin/cos table ----
static __device__ void tr64(const float* __restrict__ s, u16* __restrict__ d,
                            int sRS, int dRS, float (*t)[65], int tid){
  #pragma unroll
  for(int i = 0; i < 16; i++){
    int idx = tid + 256 * i;
    t[idx >> 6][idx & 63] = s[(long)(idx >> 6) * sRS + (idx & 63)];
  }
  __syncthreads();
  #pragma unroll
  for(int i = 0; i < 16; i++){
    int idx = tid + 256 * i;
    d[(long)(idx >> 6) * dRS + (idx & 63)] = f2b(t[idx & 63][idx >> 6]);
  }
}

__global__ __launch_bounds__(256) void k_prep(
    const float* __restrict__ x, u16* __restrict__ xb,
    const float* __restrict__ wq, u16* __restrict__ wq_t,
    const float* __restrict__ wkv, u16* __restrict__ wkv_t,
    const float* __restrict__ wo, u16* __restrict__ wo_t,
    const int* __restrict__ pos, float* __restrict__ tab){
  __shared__ float t[64][65];
  int blk = blockIdx.x, tid = threadIdx.x;
  if(blk < 8192){                               // x fp32 -> bf16
    int i = blk * 256 + tid;
    float4 v = ((const float4*)x)[i];
    ushort4 o = make_ushort4(f2b(v.x), f2b(v.y), f2b(v.z), f2b(v.w));
    ((ushort4*)xb)[i] = o;
  } else if(blk < 9216){                        // w_q [16][2048][128] -> [16][128][2048]
    int q = blk - 8192;
    int bx = q & 1, by = (q >> 1) & 31, bz = q >> 6;
    tr64(wq + (long)bz * 262144 + (long)by * 64 * 128 + bx * 64,
         wq_t + (long)bz * 262144 + (long)bx * 64 * 2048 + by * 64, 128, 2048, t, tid);
  } else if(blk < 10240){                       // w_kv [16][2048][128] -> [16][128][2048]
    int q = blk - 9216;
    int bx = q & 1, by = (q >> 1) & 31, bz = q >> 6;
    tr64(wkv + (long)bz * 262144 + (long)by * 64 * 128 + bx * 64,
         wkv_t + (long)bz * 262144 + (long)bx * 64 * 2048 + by * 64, 128, 2048, t, tid);
  } else if(blk < 11264){                       // w_out [2048][2048] -> transpose
    int q = blk - 10240;
    int bx = q & 31, by = q >> 5;
    tr64(wo + (long)by * 64 * 2048 + bx * 64,
         wo_t + (long)bx * 64 * 2048 + by * 64, 2048, 2048, t, tid);
  } else {                                      // sin/cos: tab[row][0:64]=sin, [64:128]=cos
    int idx = (blk - 11264) * 256 + tid;        // 262,144 = 4096 rows x 64 h
    int row = idx >> 6, h = idx & 63;
    float pf = (float)pos[row];
    float inv = exp2f(-0.20762050593045077f * (float)h);  // 10000^(-h/64)
    float ang = pf * inv;
    tab[(row << 7) + h]      = sinf(ang);
    tab[(row << 7) + 64 + h] = cosf(ang);
  }
}

// ---- fused QKV projection GEMM + RoPE + V-transpose epilogue ---------------
// 256x256 tile, BK=64, 512 threads = 8 waves (2M x 4N). LDS (160 KiB):
//   lds[0 .. 49152)  : A-ring, 12 slots x 4096 elems (quarter-tile 64rows x 64K)
//   lds[49152 .. end): B double buffer, 2 x 16384 elems ([4 quarters][64c][64K])
// A quarter (tile t, q) lives in slot (4t+q)%12, staged (1/phase) during tile
// t-2 => 4-8 phases of landing slack; overwrite at tile t kills A(t-1,*),
// dead >=1 barrier earlier. B(t+2) global->reg loads issued at t p0 (16B x4
// per thread), ds_written to buf (t+1)&1 at t+1 p0 (compiler auto-vmcnt),
// read at t+2. Per-K-tile checkpoint: vmcnt(8) at p3 (= 4 A-DMAs + 4 B-loads
// of this tile outstanding) => tile t+1 operands fully landed.
// Phases as R7: (m0,n01)(m1,n01)(m1,n23)(m0,n23), 16 MFMA each, plain
// s_barrier + lgkmcnt(0) + setprio, no sched_barrier.
// nt<8 -> q heads 2nt,2nt+1 ; 8..11 -> k ; 12..15 -> v (transposed).
#define STAGE_AQ(tt, q) do{ \
  gload16(Ag + (tt) * 64 + (q) * 131072, ldA + ssA * 4096); \
  ssA++; if(ssA == 12) ssA = 0; }while(0)

__global__ __launch_bounds__(512, 2) void k_gemm_qkv(
    const u16* __restrict__ A, const u16* __restrict__ wq_t, const u16* __restrict__ wkv_t,
    const float* __restrict__ tab,
    u16* __restrict__ qb, u16* __restrict__ kb, u16* __restrict__ vtp){
  __shared__ __attribute__((aligned(16))) u16 lds[81920];   // 160 KiB
  int lin = blockIdx.x + (blockIdx.y << 4);
  int xcd = lin & 7, jj = lin >> 3;             // bijective XCD swizzle:
  int mt = (xcd & 3) * 4 + (jj & 3);            // each XCD owns a 4mt x 8nt
  int nt = (xcd >> 2) * 8 + (jj >> 2);          // rectangle of the grid
  const u16* Bt = (nt < 8) ? (wq_t + (long)nt * 524288)
                           : (wkv_t + (long)(nt - 8) * 524288);
  int tid = threadIdx.x;
  int lane = tid & 63, wave = tid >> 6, l15 = lane & 15, quad = lane >> 4;
  int wr = wave >> 2, wc = wave & 3;            // 2M x 4N wave grid
  int cq0 = quad ^ (l15 & 7), cq1 = cq0 ^ 4;    // swizzled chunk, ks=0 / ks=1
  int srow = tid >> 3;
  int gch  = (tid & 7) ^ (srow & 7);            // XOR-swizzled staging chunks
  const u16* Ag = A  + ((long)mt * 256 + srow) * 2048 + (gch << 3);
  const u16* Bg = Bt + (long)srow * 2048 + (gch << 3);
  u16* bbuf = lds + 49152;
  u16* ldA = lds + tid * 8;                     // A-ring lane base
  u16* ldB = bbuf + tid * 8;                    // B dbuf lane base
  int aB = l15 << 6;                            // in-quarter row offset (A and B)
  int sa0 = 2 * wr;                             // A slot, quarter 2wr, tile 0
  int ssA = 0;                                  // A stage slot counter
  floatx4 acc[8][4];
  const floatx4 fz = {0.f, 0.f, 0.f, 0.f};
  #pragma unroll
  for(int m = 0; m < 8; m++)
    #pragma unroll
    for(int n = 0; n < 4; n++) acc[m][n] = fz;

  // ---- prologue: B(0)->reg, A(0),A(1)->ring, B(1)->reg, write B(0) --------
  short8 bp0 = *(const short8*)(Bg);
  short8 bp1 = *(const short8*)(Bg + 131072);
  short8 bp2 = *(const short8*)(Bg + 262144);
  short8 bp3 = *(const short8*)(Bg + 393216);
  STAGE_AQ(0, 0); STAGE_AQ(0, 1); STAGE_AQ(0, 2); STAGE_AQ(0, 3);
  STAGE_AQ(1, 0); STAGE_AQ(1, 1); STAGE_AQ(1, 2); STAGE_AQ(1, 3);
  short8 bc0 = *(const short8*)(Bg + 64);
  short8 bc1 = *(const short8*)(Bg + 64 + 131072);
  short8 bc2 = *(const short8*)(Bg + 64 + 262144);
  short8 bc3 = *(const short8*)(Bg + 64 + 393216);
  *(short8*)(ldB)         = bp0;                // B(0) -> buf0 (auto vmcnt)
  *(short8*)(ldB + 4096)  = bp1;
  *(short8*)(ldB + 8192)  = bp2;
  *(short8*)(ldB + 12288) = bp3;
  asm volatile("s_waitcnt vmcnt(8)" ::: "memory");  // A(0) landed
  asm volatile("s_waitcnt lgkmcnt(0)");
  __builtin_amdgcn_s_barrier();

  #pragma unroll 1
  for(int t = 0; t < 32; t++){
    const u16* aQ0 = lds + sa0 * 4096;          // quarter 2wr  (rows wr*128+0..63)
    const u16* aQ1 = lds + sa0 * 4096 + 4096;   // quarter 2wr+1 (rows +64..127)
    const u16* bS  = bbuf + (t & 1) * 16384 + wc * 4096;
    int tA = (t < 30) ? t + 2 : 31;             // clamped tail (dummy re-loads)
    short8 a0[4], a1[4], b0[2], b1[2];
    // ---- p0: B(t+2)->reg issue | write B(t+1) | quadrant (m0, n0..1) ------
    short8 bn0 = *(const short8*)(Bg + tA * 64);
    short8 bn1 = *(const short8*)(Bg + tA * 64 + 131072);
    short8 bn2 = *(const short8*)(Bg + tA * 64 + 262144);
    short8 bn3 = *(const short8*)(Bg + tA * 64 + 393216);
    {
      u16* bw = ldB + ((t + 1) & 1) * 16384;    // write B(t+1) from regs
      *(short8*)(bw)         = bc0;
      *(short8*)(bw + 4096)  = bc1;
      *(short8*)(bw + 8192)  = bc2;
      *(short8*)(bw + 12288) = bc3;
    }
    #pragma unroll
    for(int n = 0; n < 2; n++){
      b0[n] = *(const short8*)(bS + aB + (n << 10) + (cq0 << 3));
      b1[n] = *(const short8*)(bS + aB + (n << 10) + (cq1 << 3));
    }
    #pragma unroll
    for(int m = 0; m < 4; m++){
      a0[m] = *(const short8*)(aQ0 + aB + (m << 10) + (cq0 << 3));
      a1[m] = *(const short8*)(aQ0 + aB + (m << 10) + (cq1 << 3));
    }
    STAGE_AQ(tA, 0);
    __builtin_amdgcn_s_barrier();
    asm volatile("s_waitcnt lgkmcnt(0)");
    __builtin_amdgcn_s_setprio(1);
    #pragma unroll
    for(int m = 0; m < 4; m++)
      #pragma unroll
      for(int n = 0; n < 2; n++)
        acc[m][n] = __builtin_amdgcn_mfma_f32_16x16x32_bf16(a0[m], b0[n], acc[m][n], 0, 0, 0);
    #pragma unroll
    for(int m = 0; m < 4; m++)
      #pragma unroll
      for(int n = 0; n < 2; n++)
        acc[m][n] = __builtin_amdgcn_mfma_f32_16x16x32_bf16(a1[m], b1[n], acc[m][n], 0, 0, 0);
    __builtin_amdgcn_s_setprio(0);
    __builtin_amdgcn_s_barrier();
    // ---- p1: quadrant (m1, n0..1) — A quarter 2wr+1, reuse b --------------
    #pragma unroll
    for(int m = 0; m < 4; m++){
      a0[m] = *(const short8*)(aQ1 + aB + (m << 10) + (cq0 << 3));
      a1[m] = *(const short8*)(aQ1 + aB + (m << 10) + (cq1 << 3));
    }
    STAGE_AQ(tA, 1);
    __builtin_amdgcn_s_barrier();
    asm volatile("s_waitcnt lgkmcnt(0)");
    __builtin_amdgcn_s_setprio(1);
    #pragma unroll
    for(int m = 0; m < 4; m++)
      #pragma unroll
      for(int n = 0; n < 2; n++)
        acc[4 + m][n] = __builtin_amdgcn_mfma_f32_16x16x32_bf16(a0[m], b0[n], acc[4 + m][n], 0, 0, 0);
    #pragma unroll
    for(int m = 0; m < 4; m++)
      #pragma unroll
      for(int n = 0; n < 2; n++)
        acc[4 + m][n] = __builtin_amdgcn_mfma_f32_16x16x32_bf16(a1[m], b1[n], acc[4 + m][n], 0, 0, 0);
    __builtin_amdgcn_s_setprio(0);
    __builtin_amdgcn_s_barrier();
    // ---- p2: quadrant (m1, n2..3) — B cols 32..63 of quarter, reuse a -----
    #pragma unroll
    for(int n = 0; n < 2; n++){
      b0[n] = *(const short8*)(bS + aB + ((2 + n) << 10) + (cq0 << 3));
      b1[n] = *(const short8*)(bS + aB + ((2 + n) << 10) + (cq1 << 3));
    }
    STAGE_AQ(tA, 2);
    __builtin_amdgcn_s_barrier();
    asm volatile("s_waitcnt lgkmcnt(0)");
    __builtin_amdgcn_s_setprio(1);
    #pragma unroll
    for(int m = 0; m < 4; m++)
      #pragma unroll
      for(int n = 0; n < 2; n++)
        acc[4 + m][2 + n] = __builtin_amdgcn_mfma_f32_16x16x32_bf16(a0[m], b0[n], acc[4 + m][2 + n], 0, 0, 0);
    #pragma unroll
    for(int m = 0; m < 4; m++)
      #pragma unroll
      for(int n = 0; n < 2; n++)
        acc[4 + m][2 + n] = __builtin_amdgcn_mfma_f32_16x16x32_bf16(a1[m], b1[n], acc[4 + m][2 + n], 0, 0, 0);
    __builtin_amdgcn_s_setprio(0);
    __builtin_amdgcn_s_barrier();
    // ---- p3: quadrant (m0, n2..3) — A quarter 2wr again + checkpoint ------
    #pragma unroll
    for(int m = 0; m < 4; m++){
      a0[m] = *(const short8*)(aQ0 + aB + (m << 10) + (cq0 << 3));
      a1[m] = *(const short8*)(aQ0 + aB + (m << 10) + (cq1 << 3));
    }
    STAGE_AQ(tA, 3);
    asm volatile("s_waitcnt vmcnt(8)" ::: "memory");  // tile t+1 fully landed
    __builtin_amdgcn_s_barrier();
    asm volatile("s_waitcnt lgkmcnt(0)");
    __builtin_amdgcn_s_setprio(1);
    #pragma unroll
    for(int m = 0; m < 4; m++)
      #pragma unroll
      for(int n = 0; n < 2; n++)
        acc[m][2 + n] = __builtin_amdgcn_mfma_f32_16x16x32_bf16(a0[m], b0[n], acc[m][2 + n], 0, 0, 0);
    #pragma unroll
    for(int m = 0; m < 4; m++)
      #pragma unroll
      for(int n = 0; n < 2; n++)
        acc[m][2 + n] = __builtin_amdgcn_mfma_f32_16x16x32_bf16(a1[m], b1[n], acc[m][2 + n], 0, 0, 0);
    __builtin_amdgcn_s_setprio(0);
    __builtin_amdgcn_s_barrier();
    bc0 = bn0; bc1 = bn1; bc2 = bn2; bc3 = bn3; // shift B reg pipeline
    sa0 += 4; if(sa0 >= 12) sa0 -= 12;
  }

  // ---- epilogue: drain DMAs, reuse lds as sT[256][132], rope/v-transpose
  asm volatile("s_waitcnt vmcnt(0)" ::: "memory");
  __syncthreads();
  u16* sT = lds;
  int grow0 = mt * 256;
  int hb = wc >> 1, wcl = wc & 1;
  #pragma unroll 1
  for(int hh = 0; hh < 2; hh++){                // two heads per 256-wide tile
    if(hb == hh){                               // stash this head's columns
      #pragma unroll
      for(int m = 0; m < 8; m++){
        int row = wr * 128 + m * 16 + quad * 4;
        #pragma unroll
        for(int n = 0; n < 4; n++){
          int colh = wcl * 64 + n * 16 + l15;
          #pragma unroll
          for(int j = 0; j < 4; j++)
            sT[(row + j) * 132 + colh] = f2b(acc[m][n][j]);
        }
      }
    }
    __syncthreads();
    if(nt < 12){                                // q or k: rope(+scale)
      float scale = (nt < 8) ? 0.08838834764831845f : 1.0f;
      u16* dst = (nt < 8) ? qb : kb;
      int dS   = (nt < 8) ? 2048 : 1024;
      int dcol = (nt < 8) ? (nt * 2 + hh) * 128 : ((nt - 8) * 2 + hh) * 128;
      #pragma unroll
      for(int it = 0; it < 16; it++){
        int idx = tid + 512 * it;               // 8192 u32 pair-words
        int row = idx >> 5, cw = idx & 31;
        int grow = grow0 + row;
        unsigned lo = *(const unsigned*)&sT[row * 132 + 2 * cw];
        unsigned hi = *(const unsigned*)&sT[row * 132 + 64 + 2 * cw];
        float2 sn = *(const float2*)&tab[(grow << 7) + 2 * cw];
        float2 cs = *(const float2*)&tab[(grow << 7) + 64 + 2 * cw];
        float x1a = b2f((u16)lo), x1b = b2f((u16)(lo >> 16));
        float x2a = b2f((u16)hi), x2b = b2f((u16)(hi >> 16));
        float o1a = (x1a * cs.x - x2a * sn.x) * scale;
        float o1b = (x1b * cs.y - x2b * sn.y) * scale;
        float o2a = (x2a * cs.x + x1a * sn.x) * scale;
        float o2b = (x2b * cs.y + x1b * sn.y) * scale;
        unsigned w1 = (unsigned)f2b(o1a) | ((unsigned)f2b(o1b) << 16);
        unsigned w2 = (unsigned)f2b(o2a) | ((unsigned)f2b(o2b) << 16);
        *(unsigned*)&dst[(long)grow * dS + dcol + 2 * cw] = w1;
        *(unsigned*)&dst[(long)grow * dS + dcol + 64 + 2 * cw] = w2;
      }
    } else {                                    // v: transposed -> v_t[b][kv][h][s]
      int b = mt >> 3, kvh = (nt - 12) * 2 + hh;
      u16* vt = vtp + (long)(b * 8 + kvh) * 262144;
      int tcol0 = (mt & 7) * 256;
      int h = tid >> 2, s0 = (tid & 3) * 64;
      #pragma unroll
      for(int i = 0; i < 16; i++){
        int s = s0 + i * 4;
        ushort4 v4 = make_ushort4(sT[(s    ) * 132 + h], sT[(s + 1) * 132 + h],
                                  sT[(s + 2) * 132 + h], sT[(s + 3) * 132 + h]);
        *(ushort4*)&vt[(long)h * 2048 + tcol0 + s] = v4;
      }
    }
    __syncthreads();
  }
}
#undef STAGE_AQ

// ---- out projection GEMM: enc[4096x2048] x w_out^T -> fp32 out -------------
__global__ __launch_bounds__(256) void k_gemm_out(
    const u16* __restrict__ A, const u16* __restrict__ Bt0, float* __restrict__ C){
  __shared__ __attribute__((aligned(16))) u16 sA[128 * 64];
  __shared__ __attribute__((aligned(16))) u16 sB[128 * 64];
  int mt = blockIdx.x, nt = blockIdx.y;
  const u16* Bt = Bt0 + (long)nt * 262144;
  int tid = threadIdx.x;
  int lane = tid & 63, wave = tid >> 6, l15 = lane & 15, quad = lane >> 4;
  int ro = (wave & 1) * 64, co = (wave >> 1) * 64;
  int xm7 = l15 & 7;
  int srow = tid >> 3;
  int gch  = (tid & 7) ^ (srow & 7);
  const u16* Ag = A  + ((long)(mt * 128) + srow) * 2048 + (gch << 3);
  const u16* Bg = Bt + (long)srow * 2048 + (gch << 3);
  u16* lA = sA + tid * 8;
  u16* lB = sB + tid * 8;
  floatx4 acc[4][4];
  const floatx4 fz = {0.f, 0.f, 0.f, 0.f};
  #pragma unroll
  for(int r = 0; r < 4; r++)
    #pragma unroll
    for(int c = 0; c < 4; c++) acc[r][c] = fz;
  for(int k0 = 0; k0 < 2048; k0 += 64){
    #pragma unroll
    for(int r = 0; r < 4; r++){
      gload16(Ag + (long)r * 65536 + k0, lA + r * 2048);
      gload16(Bg + (long)r * 65536 + k0, lB + r * 2048);
    }
    __syncthreads();
    #pragma unroll
    for(int ks = 0; ks < 2; ks++){
      short8 af[4], bfr[4];
      #pragma unroll
      for(int r = 0; r < 4; r++)
        af[r]  = *(const short8*)(sA + ((ro + r * 16 + l15) << 6) + ((((ks << 2) | quad) ^ xm7) << 3));
      #pragma unroll
      for(int c = 0; c < 4; c++)
        bfr[c] = *(const short8*)(sB + ((co + c * 16 + l15) << 6) + ((((ks << 2) | quad) ^ xm7) << 3));
      #pragma unroll
      for(int r = 0; r < 4; r++)
        #pragma unroll
        for(int c = 0; c < 4; c++)
          acc[r][c] = __builtin_amdgcn_mfma_f32_16x16x32_bf16(af[r], bfr[c], acc[r][c], 0, 0, 0);
    }
    __syncthreads();
  }
  long rb0 = (long)mt * 128 + ro + quad * 4;
  #pragma unroll
  for(int r = 0; r < 4; r++)
    #pragma unroll
    for(int c = 0; c < 4; c++){
      int col = nt * 128 + co + c * 16 + l15;
      #pragma unroll
      for(int j = 0; j < 4; j++)
        C[(rb0 + r * 16 + j) * 2048 + col] = acc[r][c][j];
    }
}

// ---- flash attention v3.1 --------------------------------------------------
// Q-tile 64 (4 waves x 16 rows), K-tile 64, causal, fixed-max softmax
// (softcap bounds z to [-50,50] so p=e^z is safe). K/V staged by
// global_load_lds into double-buffered XOR-swizzled LDS; one barrier/tile;
// DMA for tile kt+1 flies during compute of tile kt. Diag/non-diag split.
__global__ __launch_bounds__(256) void k_flash(
    const u16* __restrict__ qb, const u16* __restrict__ kb,
    const u16* __restrict__ vt, u16* __restrict__ enc){
  __shared__ __attribute__((aligned(16))) u16 sK[2 * 64 * 128];   // 32 KB
  __shared__ __attribute__((aligned(16))) u16 sVt[2 * 128 * 64];  // 32 KB
  __shared__ __attribute__((aligned(16))) u16 sP[4][16][72];      // 9 KB
  int qt = 31 - blockIdx.y;                    // longest blocks dispatch first
  int hidx = blockIdx.x;
  int b = hidx >> 4, kv = (hidx >> 1) & 7, g = hidx & 1;
  int tid = threadIdx.x;
  int lane = tid & 63, wave = tid >> 6, l15 = lane & 15, quad = lane >> 4;

  short8 qf[4];
  {
    const u16* qg = qb + ((long)b * 2048 + qt * 64 + wave * 16 + l15) * 2048
                       + (kv * 2 + g) * 128 + quad * 8;
    #pragma unroll
    for(int ks = 0; ks < 4; ks++) qf[ks] = *(const short8*)(qg + ks * 32);
  }

  int krow = tid >> 4;
  int kch  = (tid & 15) ^ krow;
  const u16* Kg = kb + ((long)b * 2048 + krow) * 1024 + kv * 128 + (kch << 3);
  int vrow = tid >> 3;
  int vch  = (tid & 7) ^ (vrow & 7);
  const u16* Vg = vt + ((long)(b * 8 + kv) * 128 + vrow) * 2048 + (vch << 3);
  u16* lK = sK  + tid * 8;
  u16* lV = sVt + tid * 8;
  #pragma unroll
  for(int r = 0; r < 4; r++){                   // preload tile 0 -> buf 0
    gload16(Kg + (long)r * 16384, lK + r * 2048);
    gload16(Vg + (long)r * 65536, lV + r * 2048);
  }

  float l_loc[4] = {0.f, 0.f, 0.f, 0.f};
  floatx4 o_acc[8];
  const floatx4 fz = {0.f, 0.f, 0.f, 0.f};
  #pragma unroll
  for(int c = 0; c < 8; c++) o_acc[c] = fz;

  const float c1 = 0.057707801635558536f;      // 2*log2(e)/50
  const float c2 = -144.26950408889634f;       // -100*log2(e)
  const float c3 = 72.13475204444817f;         // 50*log2(e)

  for(int kt = 0; kt <= qt; kt++){
    int buf = (kt & 1) * 8192;
    __syncthreads();                           // drains DMAs for this buf + frees other buf
    if(kt < qt){                               // async stage tile kt+1 into other buf
      int nb = buf ^ 8192;
      #pragma unroll
      for(int r = 0; r < 4; r++){
        gload16(Kg + (long)(kt + 1) * 65536 + (long)r * 16384, lK + nb + r * 2048);
        gload16(Vg + (kt + 1) * 64 + (long)r * 65536, lV + nb + r * 2048);
      }
    }
    // S = Q K^T
    floatx4 s_acc[4];
    #pragma unroll
    for(int c = 0; c < 4; c++) s_acc[c] = fz;
    #pragma unroll
    for(int ks = 0; ks < 4; ks++){
      #pragma unroll
      for(int cb = 0; cb < 4; cb++){
        short8 bk = *(const short8*)(sK + buf + ((cb * 16 + l15) << 7)
                                     + ((((ks << 2) | quad) ^ l15) << 3));
        s_acc[cb] = __builtin_amdgcn_mfma_f32_16x16x32_bf16(qf[ks], bk, s_acc[cb], 0, 0, 0);
      }
    }
    // p = exp(50*tanh(s/50)) = exp2(c2/(u+1) + c3), u = exp2(c1*s)
    if(kt < qt){                               // off-diagonal: no mask
      #pragma unroll
      for(int r = 0; r < 4; r++){
        #pragma unroll
        for(int cb = 0; cb < 4; cb++){
          float s = s_acc[cb][r];
          float u = __builtin_amdgcn_exp2f(c1 * s);
          float d = __builtin_amdgcn_rcpf(u + 1.f);
          float p = __builtin_amdgcn_exp2f(__builtin_fmaf(c2, d, c3));
          l_loc[r] += p;
          sP[wave][quad * 4 + r][cb * 16 + l15] = f2b(p);
        }
      }
    } else {                                   // diagonal tile: causal mask
      int rloc = wave * 16 + quad * 4;
      #pragma unroll
      for(int r = 0; r < 4; r++){
        #pragma unroll
        for(int cb = 0; cb < 4; cb++){
          float s = s_acc[cb][r];
          float u = __builtin_amdgcn_exp2f(c1 * s);
          float d = __builtin_amdgcn_rcpf(u + 1.f);
          float p = __builtin_amdgcn_exp2f(__builtin_fmaf(c2, d, c3));
          if(cb * 16 + l15 > rloc + r) p = 0.f;
          l_loc[r] += p;
          sP[wave][quad * 4 + r][cb * 16 + l15] = f2b(p);
        }
      }
    }
    // O += P V
    #pragma unroll
    for(int ks2 = 0; ks2 < 2; ks2++){
      short8 ap = *(const short8*)&sP[wave][l15][ks2 * 32 + quad * 8];
      #pragma unroll
      for(int c = 0; c < 8; c++){
        short8 bv = *(const short8*)(sVt + buf + ((c * 16 + l15) << 6)
                                     + ((((ks2 << 2) | quad) ^ (l15 & 7)) << 3));
        o_acc[c] = __builtin_amdgcn_mfma_f32_16x16x32_bf16(ap, bv, o_acc[c], 0, 0, 0);
      }
    }
  }
  #pragma unroll
  for(int r = 0; r < 4; r++){
    float l = l_loc[r];
    #pragma unroll
    for(int off = 1; off < 16; off <<= 1) l += __shfl_xor(l, off);
    float invl = 1.f / l;
    long rowe = (long)b * 2048 + qt * 64 + wave * 16 + quad * 4 + r;
    #pragma unroll
    for(int c = 0; c < 8; c++)
      enc[rowe * 2048 + (kv * 2 + g) * 128 + c * 16 + l15] = f2b(o_acc[c][r] * invl);
  }
}

// ---------------------------------------------------------------------------
extern "C" void kernel_launch(void* const* d_in, const int* in_sizes, int n_in,
                              void* d_out, int out_size, void* d_ws, size_t ws_size,
                              hipStream_t stream){
  const float* x     = (const float*)d_in[0];
  const int*   posi  = (const int*)  d_in[1];
  // d_in[2] = attn_mask (causal, known analytically) -- unused
  const float* w_q   = (const float*)d_in[3];
  const float* w_kv  = (const float*)d_in[4];
  const float* w_out = (const float*)d_in[5];
  float* out = (float*)d_out;

  char* w = (char*)d_ws;                        // 78 MB used
  u16* xb     = (u16*)(w);                      // 16 MB (reused as enc after qkv)
  u16* wq_t   = (u16*)(w + 16777216);           //  8 MB [16][128][2048]
  u16* wkv_t  = (u16*)(w + 25165824);           //  8 MB [2][8][128][2048]
  u16* wout_t = (u16*)(w + 33554432);           //  8 MB [2048][2048]
  u16* q_buf  = (u16*)(w + 41943040);           // 16 MB [4096][2048]
  u16* k_buf  = (u16*)(w + 58720256);           //  8 MB [4096][1024]
  u16* v_t    = (u16*)(w + 67108864);           //  8 MB [2][8][128][2048]
  float* tab  = (float*)(w + 75497472);         //  2 MB sin/cos
  u16* enc    = xb;                             // xb dead after qkv

  k_prep    <<<12288, 256, 0, stream>>>(x, xb, w_q, wq_t, w_kv, wkv_t, w_out, wout_t, posi, tab);
  k_gemm_qkv<<<dim3(16, 16), 512, 0, stream>>>(xb, wq_t, wkv_t, tab, q_buf, k_buf, v_t);
  k_flash   <<<dim3(32, 32), 256, 0, stream>>>(q_buf, k_buf, v_t, enc);
  k_gemm_out<<<dim3(32, 16), 256, 0, stream>>>(enc, wout_t, out);
}

// Round 5
// 311.928 us; speedup vs baseline: 1.0992x; 1.0286x over previous
//
#include <hip/hip_runtime.h>

// ---------------------------------------------------------------------------
// Attention (GQA + RoPE + softcap + causal) on gfx950, bf16 MFMA pipeline.
// B=2 T=2048 D=2048, NH=16 NKV=8 HD=128, softcap=50, causal.
// R9: k_gemm_qkv 3-phase held-A schedule. Serial-cost model: LDS reads and
//     MFMA are serialized by the barrier discipline, so cut reads 32->24 KB
//     per wave per K-tile (hold A-m0 frags in regs across the K-tile) and
//     barriers 8->6 (merge the two n23 quadrants into one 32-MFMA region).
//     All-DMA 10-slot ring (R7) + bijective XCD swizzle (R8). B reg-staging
//     reverted (its ds_writes added LDS-port traffic).
// ---------------------------------------------------------------------------

typedef unsigned short u16;
typedef __attribute__((ext_vector_type(8))) short short8;   // 8 x bf16 (4 VGPRs)
typedef __attribute__((ext_vector_type(4))) float floatx4;  // MFMA acc

static __device__ __forceinline__ u16 f2b(float f){
  unsigned u = __float_as_uint(f);
  u = (u + 0x7fffu + ((u >> 16) & 1u)) >> 16;   // RNE
  return (u16)u;
}
static __device__ __forceinline__ float b2f(u16 u){
  return __uint_as_float(((unsigned)u) << 16);
}
// async global->LDS DMA, 16B per lane; LDS dest = wave-uniform base + lane*16
static __device__ __forceinline__ void gload16(const u16* g, u16* l){
  __builtin_amdgcn_global_load_lds(
      (const __attribute__((address_space(1))) unsigned int*)g,
      (__attribute__((address_space(3))) unsigned int*)l, 16, 0, 0);
}

// ---- prep: x->bf16 | w_q/w_kv/w_out transpose->B^T bf16 | sin/cos table ----
static __device__ void tr64(const float* __restrict__ s, u16* __restrict__ d,
                            int sRS, int dRS, float (*t)[65], int tid){
  #pragma unroll
  for(int i = 0; i < 16; i++){
    int idx = tid + 256 * i;
    t[idx >> 6][idx & 63] = s[(long)(idx >> 6) * sRS + (idx & 63)];
  }
  __syncthreads();
  #pragma unroll
  for(int i = 0; i < 16; i++){
    int idx = tid + 256 * i;
    d[(long)(idx >> 6) * dRS + (idx & 63)] = f2b(t[idx & 63][idx >> 6]);
  }
}

__global__ __launch_bounds__(256) void k_prep(
    const float* __restrict__ x, u16* __restrict__ xb,
    const float* __restrict__ wq, u16* __restrict__ wq_t,
    const float* __restrict__ wkv, u16* __restrict__ wkv_t,
    const float* __restrict__ wo, u16* __restrict__ wo_t,
    const int* __restrict__ pos, float* __restrict__ tab){
  __shared__ float t[64][65];
  int blk = blockIdx.x, tid = threadIdx.x;
  if(blk < 8192){                               // x fp32 -> bf16
    int i = blk * 256 + tid;
    float4 v = ((const float4*)x)[i];
    ushort4 o = make_ushort4(f2b(v.x), f2b(v.y), f2b(v.z), f2b(v.w));
    ((ushort4*)xb)[i] = o;
  } else if(blk < 9216){                        // w_q [16][2048][128] -> [16][128][2048]
    int q = blk - 8192;
    int bx = q & 1, by = (q >> 1) & 31, bz = q >> 6;
    tr64(wq + (long)bz * 262144 + (long)by * 64 * 128 + bx * 64,
         wq_t + (long)bz * 262144 + (long)bx * 64 * 2048 + by * 64, 128, 2048, t, tid);
  } else if(blk < 10240){                       // w_kv [16][2048][128] -> [16][128][2048]
    int q = blk - 9216;
    int bx = q & 1, by = (q >> 1) & 31, bz = q >> 6;
    tr64(wkv + (long)bz * 262144 + (long)by * 64 * 128 + bx * 64,
         wkv_t + (long)bz * 262144 + (long)bx * 64 * 2048 + by * 64, 128, 2048, t, tid);
  } else if(blk < 11264){                       // w_out [2048][2048] -> transpose
    int q = blk - 10240;
    int bx = q & 31, by = q >> 5;
    tr64(wo + (long)by * 64 * 2048 + bx * 64,
         wo_t + (long)bx * 64 * 2048 + by * 64, 2048, 2048, t, tid);
  } else {                                      // sin/cos: tab[row][0:64]=sin, [64:128]=cos
    int idx = (blk - 11264) * 256 + tid;        // 262,144 = 4096 rows x 64 h
    int row = idx >> 6, h = idx & 63;
    float pf = (float)pos[row];
    float inv = exp2f(-0.20762050593045077f * (float)h);  // 10000^(-h/64)
    float ang = pf * inv;
    tab[(row << 7) + h]      = sinf(ang);
    tab[(row << 7) + 64 + h] = cosf(ang);
  }
}

// ---- fused QKV projection GEMM + RoPE + V-transpose epilogue ---------------
// 256x256 tile, BK=64, 512 threads = 8 waves (2M x 4N), wave owns 128x64
// (acc[8][4]). 3 phases per K-tile:
//   p0: read B-n01(4) + A-m0(8, HELD) | stage B(t+1)h0,h1 | bar | 16 MFMA | bar
//   p1: read A-m1(8)                  | stage A(t+2)h0    | bar | 16 MFMA | bar
//   p2: read B-n23(4)                 | stage A(t+2)h1 + vmcnt(4) | bar |
//       32 MFMA: (m1,n23) then (m0,n23) from held A-m0 | bar
// 24 ds_read_b128/wave/K-tile (the floor for this tiling), 6 barriers/K-tile.
// 10-slot x 16KB half-tile DMA ring; tile t reads slots {4t..4t+3}%10;
// stage counter = phase slot %10; every slot overwrite is >=1 full barrier
// after all waves' read-completing lgkmcnt (verified under 3-phase order);
// vmcnt(4) at p2 => tile t+1 (B staged t p0, A staged t-1 p1/p2) landed.
// nt<8 -> q heads 2nt,2nt+1 ; 8..11 -> k ; 12..15 -> v (transposed).
#define STAGE_A(tt, h) do{ \
  const u16* s_ = Ag + (tt) * 64 + (h) * 262144; \
  u16* d_ = ld + ss * 8192; \
  gload16(s_, d_); gload16(s_ + 131072, d_ + 4096); \
  ss++; if(ss == 10) ss = 0; }while(0)
#define STAGE_B(tt, h) do{ \
  const u16* s_ = Bg + (tt) * 64 + (h) * 262144; \
  u16* d_ = ld + ss * 8192; \
  gload16(s_, d_); gload16(s_ + 131072, d_ + 4096); \
  ss++; if(ss == 10) ss = 0; }while(0)

__global__ __launch_bounds__(512, 2) void k_gemm_qkv(
    const u16* __restrict__ A, const u16* __restrict__ wq_t, const u16* __restrict__ wkv_t,
    const float* __restrict__ tab,
    u16* __restrict__ qb, u16* __restrict__ kb, u16* __restrict__ vtp){
  __shared__ __attribute__((aligned(16))) u16 ring[81920];  // 10 x 16KB = 160 KiB
  int lin = blockIdx.x + (blockIdx.y << 4);
  int xcd = lin & 7, jj = lin >> 3;             // bijective XCD swizzle:
  int mt = (xcd & 3) * 4 + (jj & 3);            // each XCD owns a 4mt x 8nt
  int nt = (xcd >> 2) * 8 + (jj >> 2);          // rectangle of the grid
  const u16* Bt = (nt < 8) ? (wq_t + (long)nt * 524288)
                           : (wkv_t + (long)(nt - 8) * 524288);
  int tid = threadIdx.x;
  int lane = tid & 63, wave = tid >> 6, l15 = lane & 15, quad = lane >> 4;
  int wr = wave >> 2, wc = wave & 3;            // 2M x 4N wave grid
  int cq0 = quad ^ (l15 & 7), cq1 = cq0 ^ 4;    // swizzled chunk, ks=0 / ks=1
  int srow = tid >> 3;
  int gch  = (tid & 7) ^ (srow & 7);            // XOR-swizzled staging chunks
  const u16* Ag = A  + ((long)mt * 256 + srow) * 2048 + (gch << 3);
  const u16* Bg = Bt + (long)srow * 2048 + (gch << 3);
  u16* ld = ring + tid * 8;
  int aB = l15 << 6;                            // in-slot elem offsets
  int bB = ((wc & 1) * 64 + l15) << 6;
  int sa = wr;                                  // A-slot for tile t: (4t+wr)%10
  int sb = 2 + (wc >> 1);                       // B-slot: (4t+2+(wc>>1))%10
  int ss = 0;                                   // stage slot counter (%10)
  floatx4 acc[8][4];
  const floatx4 fz = {0.f, 0.f, 0.f, 0.f};
  #pragma unroll
  for(int m = 0; m < 8; m++)
    #pragma unroll
    for(int n = 0; n < 4; n++) acc[m][n] = fz;

  // prologue: slots 0..5 = A(0)h0 A(0)h1 B(0)h0 B(0)h1 A(1)h0 A(1)h1
  STAGE_A(0, 0); STAGE_A(0, 1); STAGE_B(0, 0); STAGE_B(0, 1);
  STAGE_A(1, 0); STAGE_A(1, 1);
  asm volatile("s_waitcnt vmcnt(4)" ::: "memory");  // tile 0 landed
  __builtin_amdgcn_s_barrier();

  #pragma unroll 1
  for(int t = 0; t < 32; t++){
    const u16* aS = ring + sa * 8192;
    const u16* bS = ring + sb * 8192;
    int tB = (t < 31) ? t + 1 : 31;             // clamped tail = dummy re-reads
    int tA = (t < 30) ? t + 2 : 31;
    short8 am0k0[4], am0k1[4], am1k0[4], am1k1[4], b0[2], b1[2];
    // ---- p0: (m0, n0..1) — 12 ds_reads; A-m0 frags stay live to p2 --------
    #pragma unroll
    for(int n = 0; n < 2; n++){
      b0[n] = *(const short8*)(bS + bB + (n << 10) + (cq0 << 3));
      b1[n] = *(const short8*)(bS + bB + (n << 10) + (cq1 << 3));
    }
    #pragma unroll
    for(int m = 0; m < 4; m++){
      am0k0[m] = *(const short8*)(aS + aB + (m << 10) + (cq0 << 3));
      am0k1[m] = *(const short8*)(aS + aB + (m << 10) + (cq1 << 3));
    }
    STAGE_B(tB, 0); STAGE_B(tB, 1);
    __builtin_amdgcn_s_barrier();
    asm volatile("s_waitcnt lgkmcnt(0)");
    __builtin_amdgcn_s_setprio(1);
    #pragma unroll
    for(int m = 0; m < 4; m++)
      #pragma unroll
      for(int n = 0; n < 2; n++)
        acc[m][n] = __builtin_amdgcn_mfma_f32_16x16x32_bf16(am0k0[m], b0[n], acc[m][n], 0, 0, 0);
    #pragma unroll
    for(int m = 0; m < 4; m++)
      #pragma unroll
      for(int n = 0; n < 2; n++)
        acc[m][n] = __builtin_amdgcn_mfma_f32_16x16x32_bf16(am0k1[m], b1[n], acc[m][n], 0, 0, 0);
    __builtin_amdgcn_s_setprio(0);
    __builtin_amdgcn_s_barrier();
    // ---- p1: (m1, n0..1) — 8 ds_reads (A m1), reuse b ---------------------
    #pragma unroll
    for(int m = 0; m < 4; m++){
      am1k0[m] = *(const short8*)(aS + aB + 4096 + (m << 10) + (cq0 << 3));
      am1k1[m] = *(const short8*)(aS + aB + 4096 + (m << 10) + (cq1 << 3));
    }
    STAGE_A(tA, 0);
    __builtin_amdgcn_s_barrier();
    asm volatile("s_waitcnt lgkmcnt(0)");
    __builtin_amdgcn_s_setprio(1);
    #pragma unroll
    for(int m = 0; m < 4; m++)
      #pragma unroll
      for(int n = 0; n < 2; n++)
        acc[4 + m][n] = __builtin_amdgcn_mfma_f32_16x16x32_bf16(am1k0[m], b0[n], acc[4 + m][n], 0, 0, 0);
    #pragma unroll
    for(int m = 0; m < 4; m++)
      #pragma unroll
      for(int n = 0; n < 2; n++)
        acc[4 + m][n] = __builtin_amdgcn_mfma_f32_16x16x32_bf16(am1k1[m], b1[n], acc[4 + m][n], 0, 0, 0);
    __builtin_amdgcn_s_setprio(0);
    __builtin_amdgcn_s_barrier();
    // ---- p2: (m1, n2..3) + (m0, n2..3 from held A-m0) — 4 ds_reads --------
    #pragma unroll
    for(int n = 0; n < 2; n++){
      b0[n] = *(const short8*)(bS + bB + ((2 + n) << 10) + (cq0 << 3));
      b1[n] = *(const short8*)(bS + bB + ((2 + n) << 10) + (cq1 << 3));
    }
    STAGE_A(tA, 1);
    asm volatile("s_waitcnt vmcnt(4)" ::: "memory");  // tile t+1 fully landed
    __builtin_amdgcn_s_barrier();
    asm volatile("s_waitcnt lgkmcnt(0)");
    __builtin_amdgcn_s_setprio(1);
    #pragma unroll
    for(int m = 0; m < 4; m++)
      #pragma unroll
      for(int n = 0; n < 2; n++)
        acc[4 + m][2 + n] = __builtin_amdgcn_mfma_f32_16x16x32_bf16(am1k0[m], b0[n], acc[4 + m][2 + n], 0, 0, 0);
    #pragma unroll
    for(int m = 0; m < 4; m++)
      #pragma unroll
      for(int n = 0; n < 2; n++)
        acc[4 + m][2 + n] = __builtin_amdgcn_mfma_f32_16x16x32_bf16(am1k1[m], b1[n], acc[4 + m][2 + n], 0, 0, 0);
    #pragma unroll
    for(int m = 0; m < 4; m++)
      #pragma unroll
      for(int n = 0; n < 2; n++)
        acc[m][2 + n] = __builtin_amdgcn_mfma_f32_16x16x32_bf16(am0k0[m], b0[n], acc[m][2 + n], 0, 0, 0);
    #pragma unroll
    for(int m = 0; m < 4; m++)
      #pragma unroll
      for(int n = 0; n < 2; n++)
        acc[m][2 + n] = __builtin_amdgcn_mfma_f32_16x16x32_bf16(am0k1[m], b1[n], acc[m][2 + n], 0, 0, 0);
    __builtin_amdgcn_s_setprio(0);
    __builtin_amdgcn_s_barrier();
    sa += 4; if(sa >= 10) sa -= 10;
    sb += 4; if(sb >= 10) sb -= 10;
  }

  // ---- epilogue: drain DMAs, reuse ring as sT[256][132], rope/v-transpose
  asm volatile("s_waitcnt vmcnt(0)" ::: "memory");
  __syncthreads();
  u16* sT = ring;
  int grow0 = mt * 256;
  int hb = wc >> 1, wcl = wc & 1;
  #pragma unroll 1
  for(int hh = 0; hh < 2; hh++){                // two heads per 256-wide tile
    if(hb == hh){                               // stash this head's columns
      #pragma unroll
      for(int m = 0; m < 8; m++){
        int row = wr * 128 + m * 16 + quad * 4;
        #pragma unroll
        for(int n = 0; n < 4; n++){
          int colh = wcl * 64 + n * 16 + l15;
          #pragma unroll
          for(int j = 0; j < 4; j++)
            sT[(row + j) * 132 + colh] = f2b(acc[m][n][j]);
        }
      }
    }
    __syncthreads();
    if(nt < 12){                                // q or k: rope(+scale)
      float scale = (nt < 8) ? 0.08838834764831845f : 1.0f;
      u16* dst = (nt < 8) ? qb : kb;
      int dS   = (nt < 8) ? 2048 : 1024;
      int dcol = (nt < 8) ? (nt * 2 + hh) * 128 : ((nt - 8) * 2 + hh) * 128;
      #pragma unroll
      for(int it = 0; it < 16; it++){
        int idx = tid + 512 * it;               // 8192 u32 pair-words
        int row = idx >> 5, cw = idx & 31;
        int grow = grow0 + row;
        unsigned lo = *(const unsigned*)&sT[row * 132 + 2 * cw];
        unsigned hi = *(const unsigned*)&sT[row * 132 + 64 + 2 * cw];
        float2 sn = *(const float2*)&tab[(grow << 7) + 2 * cw];
        float2 cs = *(const float2*)&tab[(grow << 7) + 64 + 2 * cw];
        float x1a = b2f((u16)lo), x1b = b2f((u16)(lo >> 16));
        float x2a = b2f((u16)hi), x2b = b2f((u16)(hi >> 16));
        float o1a = (x1a * cs.x - x2a * sn.x) * scale;
        float o1b = (x1b * cs.y - x2b * sn.y) * scale;
        float o2a = (x2a * cs.x + x1a * sn.x) * scale;
        float o2b = (x2b * cs.y + x1b * sn.y) * scale;
        unsigned w1 = (unsigned)f2b(o1a) | ((unsigned)f2b(o1b) << 16);
        unsigned w2 = (unsigned)f2b(o2a) | ((unsigned)f2b(o2b) << 16);
        *(unsigned*)&dst[(long)grow * dS + dcol + 2 * cw] = w1;
        *(unsigned*)&dst[(long)grow * dS + dcol + 64 + 2 * cw] = w2;
      }
    } else {                                    // v: transposed -> v_t[b][kv][h][s]
      int b = mt >> 3, kvh = (nt - 12) * 2 + hh;
      u16* vt = vtp + (long)(b * 8 + kvh) * 262144;
      int tcol0 = (mt & 7) * 256;
      int h = tid >> 2, s0 = (tid & 3) * 64;
      #pragma unroll
      for(int i = 0; i < 16; i++){
        int s = s0 + i * 4;
        ushort4 v4 = make_ushort4(sT[(s    ) * 132 + h], sT[(s + 1) * 132 + h],
                                  sT[(s + 2) * 132 + h], sT[(s + 3) * 132 + h]);
        *(ushort4*)&vt[(long)h * 2048 + tcol0 + s] = v4;
      }
    }
    __syncthreads();
  }
}
#undef STAGE_A
#undef STAGE_B

// ---- out projection GEMM: enc[4096x2048] x w_out^T -> fp32 out -------------
__global__ __launch_bounds__(256) void k_gemm_out(
    const u16* __restrict__ A, const u16* __restrict__ Bt0, float* __restrict__ C){
  __shared__ __attribute__((aligned(16))) u16 sA[128 * 64];
  __shared__ __attribute__((aligned(16))) u16 sB[128 * 64];
  int mt = blockIdx.x, nt = blockIdx.y;
  const u16* Bt = Bt0 + (long)nt * 262144;
  int tid = threadIdx.x;
  int lane = tid & 63, wave = tid >> 6, l15 = lane & 15, quad = lane >> 4;
  int ro = (wave & 1) * 64, co = (wave >> 1) * 64;
  int xm7 = l15 & 7;
  int srow = tid >> 3;
  int gch  = (tid & 7) ^ (srow & 7);
  const u16* Ag = A  + ((long)(mt * 128) + srow) * 2048 + (gch << 3);
  const u16* Bg = Bt + (long)srow * 2048 + (gch << 3);
  u16* lA = sA + tid * 8;
  u16* lB = sB + tid * 8;
  floatx4 acc[4][4];
  const floatx4 fz = {0.f, 0.f, 0.f, 0.f};
  #pragma unroll
  for(int r = 0; r < 4; r++)
    #pragma unroll
    for(int c = 0; c < 4; c++) acc[r][c] = fz;
  for(int k0 = 0; k0 < 2048; k0 += 64){
    #pragma unroll
    for(int r = 0; r < 4; r++){
      gload16(Ag + (long)r * 65536 + k0, lA + r * 2048);
      gload16(Bg + (long)r * 65536 + k0, lB + r * 2048);
    }
    __syncthreads();
    #pragma unroll
    for(int ks = 0; ks < 2; ks++){
      short8 af[4], bfr[4];
      #pragma unroll
      for(int r = 0; r < 4; r++)
        af[r]  = *(const short8*)(sA + ((ro + r * 16 + l15) << 6) + ((((ks << 2) | quad) ^ xm7) << 3));
      #pragma unroll
      for(int c = 0; c < 4; c++)
        bfr[c] = *(const short8*)(sB + ((co + c * 16 + l15) << 6) + ((((ks << 2) | quad) ^ xm7) << 3));
      #pragma unroll
      for(int r = 0; r < 4; r++)
        #pragma unroll
        for(int c = 0; c < 4; c++)
          acc[r][c] = __builtin_amdgcn_mfma_f32_16x16x32_bf16(af[r], bfr[c], acc[r][c], 0, 0, 0);
    }
    __syncthreads();
  }
  long rb0 = (long)mt * 128 + ro + quad * 4;
  #pragma unroll
  for(int r = 0; r < 4; r++)
    #pragma unroll
    for(int c = 0; c < 4; c++){
      int col = nt * 128 + co + c * 16 + l15;
      #pragma unroll
      for(int j = 0; j < 4; j++)
        C[(rb0 + r * 16 + j) * 2048 + col] = acc[r][c][j];
    }
}

// ---- flash attention v3.1 --------------------------------------------------
// Q-tile 64 (4 waves x 16 rows), K-tile 64, causal, fixed-max softmax
// (softcap bounds z to [-50,50] so p=e^z is safe). K/V staged by
// global_load_lds into double-buffered XOR-swizzled LDS; one barrier/tile;
// DMA for tile kt+1 flies during compute of tile kt. Diag/non-diag split.
__global__ __launch_bounds__(256) void k_flash(
    const u16* __restrict__ qb, const u16* __restrict__ kb,
    const u16* __restrict__ vt, u16* __restrict__ enc){
  __shared__ __attribute__((aligned(16))) u16 sK[2 * 64 * 128];   // 32 KB
  __shared__ __attribute__((aligned(16))) u16 sVt[2 * 128 * 64];  // 32 KB
  __shared__ __attribute__((aligned(16))) u16 sP[4][16][72];      // 9 KB
  int qt = 31 - blockIdx.y;                    // longest blocks dispatch first
  int hidx = blockIdx.x;
  int b = hidx >> 4, kv = (hidx >> 1) & 7, g = hidx & 1;
  int tid = threadIdx.x;
  int lane = tid & 63, wave = tid >> 6, l15 = lane & 15, quad = lane >> 4;

  short8 qf[4];
  {
    const u16* qg = qb + ((long)b * 2048 + qt * 64 + wave * 16 + l15) * 2048
                       + (kv * 2 + g) * 128 + quad * 8;
    #pragma unroll
    for(int ks = 0; ks < 4; ks++) qf[ks] = *(const short8*)(qg + ks * 32);
  }

  int krow = tid >> 4;
  int kch  = (tid & 15) ^ krow;
  const u16* Kg = kb + ((long)b * 2048 + krow) * 1024 + kv * 128 + (kch << 3);
  int vrow = tid >> 3;
  int vch  = (tid & 7) ^ (vrow & 7);
  const u16* Vg = vt + ((long)(b * 8 + kv) * 128 + vrow) * 2048 + (vch << 3);
  u16* lK = sK  + tid * 8;
  u16* lV = sVt + tid * 8;
  #pragma unroll
  for(int r = 0; r < 4; r++){                   // preload tile 0 -> buf 0
    gload16(Kg + (long)r * 16384, lK + r * 2048);
    gload16(Vg + (long)r * 65536, lV + r * 2048);
  }

  float l_loc[4] = {0.f, 0.f, 0.f, 0.f};
  floatx4 o_acc[8];
  const floatx4 fz = {0.f, 0.f, 0.f, 0.f};
  #pragma unroll
  for(int c = 0; c < 8; c++) o_acc[c] = fz;

  const float c1 = 0.057707801635558536f;      // 2*log2(e)/50
  const float c2 = -144.26950408889634f;       // -100*log2(e)
  const float c3 = 72.13475204444817f;         // 50*log2(e)

  for(int kt = 0; kt <= qt; kt++){
    int buf = (kt & 1) * 8192;
    __syncthreads();                           // drains DMAs for this buf + frees other buf
    if(kt < qt){                               // async stage tile kt+1 into other buf
      int nb = buf ^ 8192;
      #pragma unroll
      for(int r = 0; r < 4; r++){
        gload16(Kg + (long)(kt + 1) * 65536 + (long)r * 16384, lK + nb + r * 2048);
        gload16(Vg + (kt + 1) * 64 + (long)r * 65536, lV + nb + r * 2048);
      }
    }
    // S = Q K^T
    floatx4 s_acc[4];
    #pragma unroll
    for(int c = 0; c < 4; c++) s_acc[c] = fz;
    #pragma unroll
    for(int ks = 0; ks < 4; ks++){
      #pragma unroll
      for(int cb = 0; cb < 4; cb++){
        short8 bk = *(const short8*)(sK + buf + ((cb * 16 + l15) << 7)
                                     + ((((ks << 2) | quad) ^ l15) << 3));
        s_acc[cb] = __builtin_amdgcn_mfma_f32_16x16x32_bf16(qf[ks], bk, s_acc[cb], 0, 0, 0);
      }
    }
    // p = exp(50*tanh(s/50)) = exp2(c2/(u+1) + c3), u = exp2(c1*s)
    if(kt < qt){                               // off-diagonal: no mask
      #pragma unroll
      for(int r = 0; r < 4; r++){
        #pragma unroll
        for(int cb = 0; cb < 4; cb++){
          float s = s_acc[cb][r];
          float u = __builtin_amdgcn_exp2f(c1 * s);
          float d = __builtin_amdgcn_rcpf(u + 1.f);
          float p = __builtin_amdgcn_exp2f(__builtin_fmaf(c2, d, c3));
          l_loc[r] += p;
          sP[wave][quad * 4 + r][cb * 16 + l15] = f2b(p);
        }
      }
    } else {                                   // diagonal tile: causal mask
      int rloc = wave * 16 + quad * 4;
      #pragma unroll
      for(int r = 0; r < 4; r++){
        #pragma unroll
        for(int cb = 0; cb < 4; cb++){
          float s = s_acc[cb][r];
          float u = __builtin_amdgcn_exp2f(c1 * s);
          float d = __builtin_amdgcn_rcpf(u + 1.f);
          float p = __builtin_amdgcn_exp2f(__builtin_fmaf(c2, d, c3));
          if(cb * 16 + l15 > rloc + r) p = 0.f;
          l_loc[r] += p;
          sP[wave][quad * 4 + r][cb * 16 + l15] = f2b(p);
        }
      }
    }
    // O += P V
    #pragma unroll
    for(int ks2 = 0; ks2 < 2; ks2++){
      short8 ap = *(const short8*)&sP[wave][l15][ks2 * 32 + quad * 8];
      #pragma unroll
      for(int c = 0; c < 8; c++){
        short8 bv = *(const short8*)(sVt + buf + ((c * 16 + l15) << 6)
                                     + ((((ks2 << 2) | quad) ^ (l15 & 7)) << 3));
        o_acc[c] = __builtin_amdgcn_mfma_f32_16x16x32_bf16(ap, bv, o_acc[c], 0, 0, 0);
      }
    }
  }
  #pragma unroll
  for(int r = 0; r < 4; r++){
    float l = l_loc[r];
    #pragma unroll
    for(int off = 1; off < 16; off <<= 1) l += __shfl_xor(l, off);
    float invl = 1.f / l;
    long rowe = (long)b * 2048 + qt * 64 + wave * 16 + quad * 4 + r;
    #pragma unroll
    for(int c = 0; c < 8; c++)
      enc[rowe * 2048 + (kv * 2 + g) * 128 + c * 16 + l15] = f2b(o_acc[c][r] * invl);
  }
}

// ---------------------------------------------------------------------------
extern "C" void kernel_launch(void* const* d_in, const int* in_sizes, int n_in,
                              void* d_out, int out_size, void* d_ws, size_t ws_size,
                              hipStream_t stream){
  const float* x     = (const float*)d_in[0];
  const int*   posi  = (const int*)  d_in[1];
  // d_in[2] = attn_mask (causal, known analytically) -- unused
  const float* w_q   = (const float*)d_in[3];
  const float* w_kv  = (const float*)d_in[4];
  const float* w_out = (const float*)d_in[5];
  float* out = (float*)d_out;

  char* w = (char*)d_ws;                        // 78 MB used
  u16* xb     = (u16*)(w);                      // 16 MB (reused as enc after qkv)
  u16* wq_t   = (u16*)(w + 16777216);           //  8 MB [16][128][2048]
  u16* wkv_t  = (u16*)(w + 25165824);           //  8 MB [2][8][128][2048]
  u16* wout_t = (u16*)(w + 33554432);           //  8 MB [2048][2048]
  u16* q_buf  = (u16*)(w + 41943040);           // 16 MB [4096][2048]
  u16* k_buf  = (u16*)(w + 58720256);           //  8 MB [4096][1024]
  u16* v_t    = (u16*)(w + 67108864);           //  8 MB [2][8][128][2048]
  float* tab  = (float*)(w + 75497472);         //  2 MB sin/cos
  u16* enc    = xb;                             // xb dead after qkv

  k_prep    <<<12288, 256, 0, stream>>>(x, xb, w_q, wq_t, w_kv, wkv_t, w_out, wout_t, posi, tab);
  k_gemm_qkv<<<dim3(16, 16), 512, 0, stream>>>(xb, wq_t, wkv_t, tab, q_buf, k_buf, v_t);
  k_flash   <<<dim3(32, 32), 256, 0, stream>>>(q_buf, k_buf, v_t, enc);
  k_gemm_out<<<dim3(32, 16), 256, 0, stream>>>(enc, wout_t, out);
}

// Round 6
// 311.888 us; speedup vs baseline: 1.0993x; 1.0001x over previous
//
#include <hip/hip_runtime.h>

// ---------------------------------------------------------------------------
// Attention (GQA + RoPE + softcap + causal) on gfx950, bf16 MFMA pipeline.
// B=2 T=2048 D=2048, NH=16 NKV=8 HD=128, softcap=50, causal.
// R10: k_gemm_qkv wave-drift schedule. R9's serial-cost audit closed the
//      books: per-phase barriers make LDS-read time and MFMA time additive
//      (2484 + 2313 + 512 + sync = 5850 cyc/K-tile observed). Fix: remove
//      intra-K-tile barriers; 8 waves drift so one wave's ds_reads overlap
//      another's MFMAs. ONE vmcnt(4) + ONE s_barrier per K-tile. Ring slot
//      algebra: reads {4t..4t+3}%10 vs stages {4t+6..4t+9}%10 disjoint;
//      WAR protected by the K-tile barrier; DMA visibility by per-wave
//      vmcnt(4) before that barrier. Held-A 3-group MFMA body kept from R9.
// ---------------------------------------------------------------------------

typedef unsigned short u16;
typedef __attribute__((ext_vector_type(8))) short short8;   // 8 x bf16 (4 VGPRs)
typedef __attribute__((ext_vector_type(4))) float floatx4;  // MFMA acc

static __device__ __forceinline__ u16 f2b(float f){
  unsigned u = __float_as_uint(f);
  u = (u + 0x7fffu + ((u >> 16) & 1u)) >> 16;   // RNE
  return (u16)u;
}
static __device__ __forceinline__ float b2f(u16 u){
  return __uint_as_float(((unsigned)u) << 16);
}
// async global->LDS DMA, 16B per lane; LDS dest = wave-uniform base + lane*16
static __device__ __forceinline__ void gload16(const u16* g, u16* l){
  __builtin_amdgcn_global_load_lds(
      (const __attribute__((address_space(1))) unsigned int*)g,
      (__attribute__((address_space(3))) unsigned int*)l, 16, 0, 0);
}

// ---- prep: x->bf16 | w_q/w_kv/w_out transpose->B^T bf16 | sin/cos table ----
static __device__ void tr64(const float* __restrict__ s, u16* __restrict__ d,
                            int sRS, int dRS, float (*t)[65], int tid){
  #pragma unroll
  for(int i = 0; i < 16; i++){
    int idx = tid + 256 * i;
    t[idx >> 6][idx & 63] = s[(long)(idx >> 6) * sRS + (idx & 63)];
  }
  __syncthreads();
  #pragma unroll
  for(int i = 0; i < 16; i++){
    int idx = tid + 256 * i;
    d[(long)(idx >> 6) * dRS + (idx & 63)] = f2b(t[idx & 63][idx >> 6]);
  }
}

__global__ __launch_bounds__(256) void k_prep(
    const float* __restrict__ x, u16* __restrict__ xb,
    const float* __restrict__ wq, u16* __restrict__ wq_t,
    const float* __restrict__ wkv, u16* __restrict__ wkv_t,
    const float* __restrict__ wo, u16* __restrict__ wo_t,
    const int* __restrict__ pos, float* __restrict__ tab){
  __shared__ float t[64][65];
  int blk = blockIdx.x, tid = threadIdx.x;
  if(blk < 8192){                               // x fp32 -> bf16
    int i = blk * 256 + tid;
    float4 v = ((const float4*)x)[i];
    ushort4 o = make_ushort4(f2b(v.x), f2b(v.y), f2b(v.z), f2b(v.w));
    ((ushort4*)xb)[i] = o;
  } else if(blk < 9216){                        // w_q [16][2048][128] -> [16][128][2048]
    int q = blk - 8192;
    int bx = q & 1, by = (q >> 1) & 31, bz = q >> 6;
    tr64(wq + (long)bz * 262144 + (long)by * 64 * 128 + bx * 64,
         wq_t + (long)bz * 262144 + (long)bx * 64 * 2048 + by * 64, 128, 2048, t, tid);
  } else if(blk < 10240){                       // w_kv [16][2048][128] -> [16][128][2048]
    int q = blk - 9216;
    int bx = q & 1, by = (q >> 1) & 31, bz = q >> 6;
    tr64(wkv + (long)bz * 262144 + (long)by * 64 * 128 + bx * 64,
         wkv_t + (long)bz * 262144 + (long)bx * 64 * 2048 + by * 64, 128, 2048, t, tid);
  } else if(blk < 11264){                       // w_out [2048][2048] -> transpose
    int q = blk - 10240;
    int bx = q & 31, by = q >> 5;
    tr64(wo + (long)by * 64 * 2048 + bx * 64,
         wo_t + (long)bx * 64 * 2048 + by * 64, 2048, 2048, t, tid);
  } else {                                      // sin/cos: tab[row][0:64]=sin, [64:128]=cos
    int idx = (blk - 11264) * 256 + tid;        // 262,144 = 4096 rows x 64 h
    int row = idx >> 6, h = idx & 63;
    float pf = (float)pos[row];
    float inv = exp2f(-0.20762050593045077f * (float)h);  // 10000^(-h/64)
    float ang = pf * inv;
    tab[(row << 7) + h]      = sinf(ang);
    tab[(row << 7) + 64 + h] = cosf(ang);
  }
}

// ---- fused QKV projection GEMM + RoPE + V-transpose epilogue ---------------
// 256x256 tile, BK=64, 512 threads = 8 waves (2M x 4N), wave owns 128x64
// (acc[8][4]). Per K-tile (NO intra-tile barriers — waves drift):
//   reads B-n01(4)+A-m0(8, held) | stage B(t+1)h0,h1 | 16 MFMA (m0,n01)
//   reads A-m1(8)                | stage A(t+2)h0    | 16 MFMA (m1,n01)
//   reads B-n23(4)               | stage A(t+2)h1    | 32 MFMA (m1,n23)+(m0,n23)
//   vmcnt(4) ; s_barrier
// 24 ds_read_b128/wave/K-tile, 1 barrier/K-tile. 10-slot x 16KB ring:
// tile-t reads slots {4t..4t+3}%10, stages write {4t+6..4t+9}%10 (disjoint
// under any intra-tile drift); WAR: overwritten slot last read tile t-1,
// ordered by the end-of-(t-1) barrier; visibility: every wave vmcnt(4)
// before the barrier => after it, all waves' t+1 operands landed.
// nt<8 -> q heads 2nt,2nt+1 ; 8..11 -> k ; 12..15 -> v (transposed).
#define STAGE_A(tt, h) do{ \
  const u16* s_ = Ag + (tt) * 64 + (h) * 262144; \
  u16* d_ = ld + ss * 8192; \
  gload16(s_, d_); gload16(s_ + 131072, d_ + 4096); \
  ss++; if(ss == 10) ss = 0; }while(0)
#define STAGE_B(tt, h) do{ \
  const u16* s_ = Bg + (tt) * 64 + (h) * 262144; \
  u16* d_ = ld + ss * 8192; \
  gload16(s_, d_); gload16(s_ + 131072, d_ + 4096); \
  ss++; if(ss == 10) ss = 0; }while(0)

__global__ __launch_bounds__(512, 2) void k_gemm_qkv(
    const u16* __restrict__ A, const u16* __restrict__ wq_t, const u16* __restrict__ wkv_t,
    const float* __restrict__ tab,
    u16* __restrict__ qb, u16* __restrict__ kb, u16* __restrict__ vtp){
  __shared__ __attribute__((aligned(16))) u16 ring[81920];  // 10 x 16KB = 160 KiB
  int lin = blockIdx.x + (blockIdx.y << 4);
  int xcd = lin & 7, jj = lin >> 3;             // bijective XCD swizzle:
  int mt = (xcd & 3) * 4 + (jj & 3);            // each XCD owns a 4mt x 8nt
  int nt = (xcd >> 2) * 8 + (jj >> 2);          // rectangle of the grid
  const u16* Bt = (nt < 8) ? (wq_t + (long)nt * 524288)
                           : (wkv_t + (long)(nt - 8) * 524288);
  int tid = threadIdx.x;
  int lane = tid & 63, wave = tid >> 6, l15 = lane & 15, quad = lane >> 4;
  int wr = wave >> 2, wc = wave & 3;            // 2M x 4N wave grid
  int cq0 = quad ^ (l15 & 7), cq1 = cq0 ^ 4;    // swizzled chunk, ks=0 / ks=1
  int srow = tid >> 3;
  int gch  = (tid & 7) ^ (srow & 7);            // XOR-swizzled staging chunks
  const u16* Ag = A  + ((long)mt * 256 + srow) * 2048 + (gch << 3);
  const u16* Bg = Bt + (long)srow * 2048 + (gch << 3);
  u16* ld = ring + tid * 8;
  int aB = l15 << 6;                            // in-slot elem offsets
  int bB = ((wc & 1) * 64 + l15) << 6;
  int sa = wr;                                  // A-slot for tile t: (4t+wr)%10
  int sb = 2 + (wc >> 1);                       // B-slot: (4t+2+(wc>>1))%10
  int ss = 0;                                   // stage slot counter (%10)
  floatx4 acc[8][4];
  const floatx4 fz = {0.f, 0.f, 0.f, 0.f};
  #pragma unroll
  for(int m = 0; m < 8; m++)
    #pragma unroll
    for(int n = 0; n < 4; n++) acc[m][n] = fz;

  // prologue: slots 0..5 = A(0)h0 A(0)h1 B(0)h0 B(0)h1 A(1)h0 A(1)h1
  STAGE_A(0, 0); STAGE_A(0, 1); STAGE_B(0, 0); STAGE_B(0, 1);
  STAGE_A(1, 0); STAGE_A(1, 1);
  asm volatile("s_waitcnt vmcnt(4)" ::: "memory");  // tile 0 landed
  __builtin_amdgcn_s_barrier();

  #pragma unroll 1
  for(int t = 0; t < 32; t++){
    const u16* aS = ring + sa * 8192;
    const u16* bS = ring + sb * 8192;
    int tB = (t < 31) ? t + 1 : 31;             // clamped tail = dummy re-reads
    int tA = (t < 30) ? t + 2 : 31;
    short8 am0k0[4], am0k1[4], am1k0[4], am1k1[4], b0[2], b1[2];
    // ---- group 0: (m0, n0..1) — 12 ds_reads; A-m0 frags held to group 2 ---
    #pragma unroll
    for(int n = 0; n < 2; n++){
      b0[n] = *(const short8*)(bS + bB + (n << 10) + (cq0 << 3));
      b1[n] = *(const short8*)(bS + bB + (n << 10) + (cq1 << 3));
    }
    #pragma unroll
    for(int m = 0; m < 4; m++){
      am0k0[m] = *(const short8*)(aS + aB + (m << 10) + (cq0 << 3));
      am0k1[m] = *(const short8*)(aS + aB + (m << 10) + (cq1 << 3));
    }
    STAGE_B(tB, 0); STAGE_B(tB, 1);
    __builtin_amdgcn_s_setprio(1);
    #pragma unroll
    for(int m = 0; m < 4; m++)
      #pragma unroll
      for(int n = 0; n < 2; n++)
        acc[m][n] = __builtin_amdgcn_mfma_f32_16x16x32_bf16(am0k0[m], b0[n], acc[m][n], 0, 0, 0);
    #pragma unroll
    for(int m = 0; m < 4; m++)
      #pragma unroll
      for(int n = 0; n < 2; n++)
        acc[m][n] = __builtin_amdgcn_mfma_f32_16x16x32_bf16(am0k1[m], b1[n], acc[m][n], 0, 0, 0);
    __builtin_amdgcn_s_setprio(0);
    // ---- group 1: (m1, n0..1) — 8 ds_reads (A m1), reuse b ----------------
    #pragma unroll
    for(int m = 0; m < 4; m++){
      am1k0[m] = *(const short8*)(aS + aB + 4096 + (m << 10) + (cq0 << 3));
      am1k1[m] = *(const short8*)(aS + aB + 4096 + (m << 10) + (cq1 << 3));
    }
    STAGE_A(tA, 0);
    __builtin_amdgcn_s_setprio(1);
    #pragma unroll
    for(int m = 0; m < 4; m++)
      #pragma unroll
      for(int n = 0; n < 2; n++)
        acc[4 + m][n] = __builtin_amdgcn_mfma_f32_16x16x32_bf16(am1k0[m], b0[n], acc[4 + m][n], 0, 0, 0);
    #pragma unroll
    for(int m = 0; m < 4; m++)
      #pragma unroll
      for(int n = 0; n < 2; n++)
        acc[4 + m][n] = __builtin_amdgcn_mfma_f32_16x16x32_bf16(am1k1[m], b1[n], acc[4 + m][n], 0, 0, 0);
    __builtin_amdgcn_s_setprio(0);
    // ---- group 2: (m1, n2..3) + (m0, n2..3 from held A-m0) — 4 ds_reads ---
    #pragma unroll
    for(int n = 0; n < 2; n++){
      b0[n] = *(const short8*)(bS + bB + ((2 + n) << 10) + (cq0 << 3));
      b1[n] = *(const short8*)(bS + bB + ((2 + n) << 10) + (cq1 << 3));
    }
    STAGE_A(tA, 1);
    __builtin_amdgcn_s_setprio(1);
    #pragma unroll
    for(int m = 0; m < 4; m++)
      #pragma unroll
      for(int n = 0; n < 2; n++)
        acc[4 + m][2 + n] = __builtin_amdgcn_mfma_f32_16x16x32_bf16(am1k0[m], b0[n], acc[4 + m][2 + n], 0, 0, 0);
    #pragma unroll
    for(int m = 0; m < 4; m++)
      #pragma unroll
      for(int n = 0; n < 2; n++)
        acc[4 + m][2 + n] = __builtin_amdgcn_mfma_f32_16x16x32_bf16(am1k1[m], b1[n], acc[4 + m][2 + n], 0, 0, 0);
    #pragma unroll
    for(int m = 0; m < 4; m++)
      #pragma unroll
      for(int n = 0; n < 2; n++)
        acc[m][2 + n] = __builtin_amdgcn_mfma_f32_16x16x32_bf16(am0k0[m], b0[n], acc[m][2 + n], 0, 0, 0);
    #pragma unroll
    for(int m = 0; m < 4; m++)
      #pragma unroll
      for(int n = 0; n < 2; n++)
        acc[m][2 + n] = __builtin_amdgcn_mfma_f32_16x16x32_bf16(am0k1[m], b1[n], acc[m][2 + n], 0, 0, 0);
    __builtin_amdgcn_s_setprio(0);
    // ---- K-tile boundary: publish DMAs + bound wave drift -----------------
    asm volatile("s_waitcnt vmcnt(4)" ::: "memory");  // tile t+1 fully landed
    __builtin_amdgcn_s_barrier();
    sa += 4; if(sa >= 10) sa -= 10;
    sb += 4; if(sb >= 10) sb -= 10;
  }

  // ---- epilogue: drain DMAs, reuse ring as sT[256][132], rope/v-transpose
  asm volatile("s_waitcnt vmcnt(0)" ::: "memory");
  __syncthreads();
  u16* sT = ring;
  int grow0 = mt * 256;
  int hb = wc >> 1, wcl = wc & 1;
  #pragma unroll 1
  for(int hh = 0; hh < 2; hh++){                // two heads per 256-wide tile
    if(hb == hh){                               // stash this head's columns
      #pragma unroll
      for(int m = 0; m < 8; m++){
        int row = wr * 128 + m * 16 + quad * 4;
        #pragma unroll
        for(int n = 0; n < 4; n++){
          int colh = wcl * 64 + n * 16 + l15;
          #pragma unroll
          for(int j = 0; j < 4; j++)
            sT[(row + j) * 132 + colh] = f2b(acc[m][n][j]);
        }
      }
    }
    __syncthreads();
    if(nt < 12){                                // q or k: rope(+scale)
      float scale = (nt < 8) ? 0.08838834764831845f : 1.0f;
      u16* dst = (nt < 8) ? qb : kb;
      int dS   = (nt < 8) ? 2048 : 1024;
      int dcol = (nt < 8) ? (nt * 2 + hh) * 128 : ((nt - 8) * 2 + hh) * 128;
      #pragma unroll
      for(int it = 0; it < 16; it++){
        int idx = tid + 512 * it;               // 8192 u32 pair-words
        int row = idx >> 5, cw = idx & 31;
        int grow = grow0 + row;
        unsigned lo = *(const unsigned*)&sT[row * 132 + 2 * cw];
        unsigned hi = *(const unsigned*)&sT[row * 132 + 64 + 2 * cw];
        float2 sn = *(const float2*)&tab[(grow << 7) + 2 * cw];
        float2 cs = *(const float2*)&tab[(grow << 7) + 64 + 2 * cw];
        float x1a = b2f((u16)lo), x1b = b2f((u16)(lo >> 16));
        float x2a = b2f((u16)hi), x2b = b2f((u16)(hi >> 16));
        float o1a = (x1a * cs.x - x2a * sn.x) * scale;
        float o1b = (x1b * cs.y - x2b * sn.y) * scale;
        float o2a = (x2a * cs.x + x1a * sn.x) * scale;
        float o2b = (x2b * cs.y + x1b * sn.y) * scale;
        unsigned w1 = (unsigned)f2b(o1a) | ((unsigned)f2b(o1b) << 16);
        unsigned w2 = (unsigned)f2b(o2a) | ((unsigned)f2b(o2b) << 16);
        *(unsigned*)&dst[(long)grow * dS + dcol + 2 * cw] = w1;
        *(unsigned*)&dst[(long)grow * dS + dcol + 64 + 2 * cw] = w2;
      }
    } else {                                    // v: transposed -> v_t[b][kv][h][s]
      int b = mt >> 3, kvh = (nt - 12) * 2 + hh;
      u16* vt = vtp + (long)(b * 8 + kvh) * 262144;
      int tcol0 = (mt & 7) * 256;
      int h = tid >> 2, s0 = (tid & 3) * 64;
      #pragma unroll
      for(int i = 0; i < 16; i++){
        int s = s0 + i * 4;
        ushort4 v4 = make_ushort4(sT[(s    ) * 132 + h], sT[(s + 1) * 132 + h],
                                  sT[(s + 2) * 132 + h], sT[(s + 3) * 132 + h]);
        *(ushort4*)&vt[(long)h * 2048 + tcol0 + s] = v4;
      }
    }
    __syncthreads();
  }
}
#undef STAGE_A
#undef STAGE_B

// ---- out projection GEMM: enc[4096x2048] x w_out^T -> fp32 out -------------
__global__ __launch_bounds__(256) void k_gemm_out(
    const u16* __restrict__ A, const u16* __restrict__ Bt0, float* __restrict__ C){
  __shared__ __attribute__((aligned(16))) u16 sA[128 * 64];
  __shared__ __attribute__((aligned(16))) u16 sB[128 * 64];
  int mt = blockIdx.x, nt = blockIdx.y;
  const u16* Bt = Bt0 + (long)nt * 262144;
  int tid = threadIdx.x;
  int lane = tid & 63, wave = tid >> 6, l15 = lane & 15, quad = lane >> 4;
  int ro = (wave & 1) * 64, co = (wave >> 1) * 64;
  int xm7 = l15 & 7;
  int srow = tid >> 3;
  int gch  = (tid & 7) ^ (srow & 7);
  const u16* Ag = A  + ((long)(mt * 128) + srow) * 2048 + (gch << 3);
  const u16* Bg = Bt + (long)srow * 2048 + (gch << 3);
  u16* lA = sA + tid * 8;
  u16* lB = sB + tid * 8;
  floatx4 acc[4][4];
  const floatx4 fz = {0.f, 0.f, 0.f, 0.f};
  #pragma unroll
  for(int r = 0; r < 4; r++)
    #pragma unroll
    for(int c = 0; c < 4; c++) acc[r][c] = fz;
  for(int k0 = 0; k0 < 2048; k0 += 64){
    #pragma unroll
    for(int r = 0; r < 4; r++){
      gload16(Ag + (long)r * 65536 + k0, lA + r * 2048);
      gload16(Bg + (long)r * 65536 + k0, lB + r * 2048);
    }
    __syncthreads();
    #pragma unroll
    for(int ks = 0; ks < 2; ks++){
      short8 af[4], bfr[4];
      #pragma unroll
      for(int r = 0; r < 4; r++)
        af[r]  = *(const short8*)(sA + ((ro + r * 16 + l15) << 6) + ((((ks << 2) | quad) ^ xm7) << 3));
      #pragma unroll
      for(int c = 0; c < 4; c++)
        bfr[c] = *(const short8*)(sB + ((co + c * 16 + l15) << 6) + ((((ks << 2) | quad) ^ xm7) << 3));
      #pragma unroll
      for(int r = 0; r < 4; r++)
        #pragma unroll
        for(int c = 0; c < 4; c++)
          acc[r][c] = __builtin_amdgcn_mfma_f32_16x16x32_bf16(af[r], bfr[c], acc[r][c], 0, 0, 0);
    }
    __syncthreads();
  }
  long rb0 = (long)mt * 128 + ro + quad * 4;
  #pragma unroll
  for(int r = 0; r < 4; r++)
    #pragma unroll
    for(int c = 0; c < 4; c++){
      int col = nt * 128 + co + c * 16 + l15;
      #pragma unroll
      for(int j = 0; j < 4; j++)
        C[(rb0 + r * 16 + j) * 2048 + col] = acc[r][c][j];
    }
}

// ---- flash attention v3.1 --------------------------------------------------
// Q-tile 64 (4 waves x 16 rows), K-tile 64, causal, fixed-max softmax
// (softcap bounds z to [-50,50] so p=e^z is safe). K/V staged by
// global_load_lds into double-buffered XOR-swizzled LDS; one barrier/tile;
// DMA for tile kt+1 flies during compute of tile kt. Diag/non-diag split.
__global__ __launch_bounds__(256) void k_flash(
    const u16* __restrict__ qb, const u16* __restrict__ kb,
    const u16* __restrict__ vt, u16* __restrict__ enc){
  __shared__ __attribute__((aligned(16))) u16 sK[2 * 64 * 128];   // 32 KB
  __shared__ __attribute__((aligned(16))) u16 sVt[2 * 128 * 64];  // 32 KB
  __shared__ __attribute__((aligned(16))) u16 sP[4][16][72];      // 9 KB
  int qt = 31 - blockIdx.y;                    // longest blocks dispatch first
  int hidx = blockIdx.x;
  int b = hidx >> 4, kv = (hidx >> 1) & 7, g = hidx & 1;
  int tid = threadIdx.x;
  int lane = tid & 63, wave = tid >> 6, l15 = lane & 15, quad = lane >> 4;

  short8 qf[4];
  {
    const u16* qg = qb + ((long)b * 2048 + qt * 64 + wave * 16 + l15) * 2048
                       + (kv * 2 + g) * 128 + quad * 8;
    #pragma unroll
    for(int ks = 0; ks < 4; ks++) qf[ks] = *(const short8*)(qg + ks * 32);
  }

  int krow = tid >> 4;
  int kch  = (tid & 15) ^ krow;
  const u16* Kg = kb + ((long)b * 2048 + krow) * 1024 + kv * 128 + (kch << 3);
  int vrow = tid >> 3;
  int vch  = (tid & 7) ^ (vrow & 7);
  const u16* Vg = vt + ((long)(b * 8 + kv) * 128 + vrow) * 2048 + (vch << 3);
  u16* lK = sK  + tid * 8;
  u16* lV = sVt + tid * 8;
  #pragma unroll
  for(int r = 0; r < 4; r++){                   // preload tile 0 -> buf 0
    gload16(Kg + (long)r * 16384, lK + r * 2048);
    gload16(Vg + (long)r * 65536, lV + r * 2048);
  }

  float l_loc[4] = {0.f, 0.f, 0.f, 0.f};
  floatx4 o_acc[8];
  const floatx4 fz = {0.f, 0.f, 0.f, 0.f};
  #pragma unroll
  for(int c = 0; c < 8; c++) o_acc[c] = fz;

  const float c1 = 0.057707801635558536f;      // 2*log2(e)/50
  const float c2 = -144.26950408889634f;       // -100*log2(e)
  const float c3 = 72.13475204444817f;         // 50*log2(e)

  for(int kt = 0; kt <= qt; kt++){
    int buf = (kt & 1) * 8192;
    __syncthreads();                           // drains DMAs for this buf + frees other buf
    if(kt < qt){                               // async stage tile kt+1 into other buf
      int nb = buf ^ 8192;
      #pragma unroll
      for(int r = 0; r < 4; r++){
        gload16(Kg + (long)(kt + 1) * 65536 + (long)r * 16384, lK + nb + r * 2048);
        gload16(Vg + (kt + 1) * 64 + (long)r * 65536, lV + nb + r * 2048);
      }
    }
    // S = Q K^T
    floatx4 s_acc[4];
    #pragma unroll
    for(int c = 0; c < 4; c++) s_acc[c] = fz;
    #pragma unroll
    for(int ks = 0; ks < 4; ks++){
      #pragma unroll
      for(int cb = 0; cb < 4; cb++){
        short8 bk = *(const short8*)(sK + buf + ((cb * 16 + l15) << 7)
                                     + ((((ks << 2) | quad) ^ l15) << 3));
        s_acc[cb] = __builtin_amdgcn_mfma_f32_16x16x32_bf16(qf[ks], bk, s_acc[cb], 0, 0, 0);
      }
    }
    // p = exp(50*tanh(s/50)) = exp2(c2/(u+1) + c3), u = exp2(c1*s)
    if(kt < qt){                               // off-diagonal: no mask
      #pragma unroll
      for(int r = 0; r < 4; r++){
        #pragma unroll
        for(int cb = 0; cb < 4; cb++){
          float s = s_acc[cb][r];
          float u = __builtin_amdgcn_exp2f(c1 * s);
          float d = __builtin_amdgcn_rcpf(u + 1.f);
          float p = __builtin_amdgcn_exp2f(__builtin_fmaf(c2, d, c3));
          l_loc[r] += p;
          sP[wave][quad * 4 + r][cb * 16 + l15] = f2b(p);
        }
      }
    } else {                                   // diagonal tile: causal mask
      int rloc = wave * 16 + quad * 4;
      #pragma unroll
      for(int r = 0; r < 4; r++){
        #pragma unroll
        for(int cb = 0; cb < 4; cb++){
          float s = s_acc[cb][r];
          float u = __builtin_amdgcn_exp2f(c1 * s);
          float d = __builtin_amdgcn_rcpf(u + 1.f);
          float p = __builtin_amdgcn_exp2f(__builtin_fmaf(c2, d, c3));
          if(cb * 16 + l15 > rloc + r) p = 0.f;
          l_loc[r] += p;
          sP[wave][quad * 4 + r][cb * 16 + l15] = f2b(p);
        }
      }
    }
    // O += P V
    #pragma unroll
    for(int ks2 = 0; ks2 < 2; ks2++){
      short8 ap = *(const short8*)&sP[wave][l15][ks2 * 32 + quad * 8];
      #pragma unroll
      for(int c = 0; c < 8; c++){
        short8 bv = *(const short8*)(sVt + buf + ((c * 16 + l15) << 6)
                                     + ((((ks2 << 2) | quad) ^ (l15 & 7)) << 3));
        o_acc[c] = __builtin_amdgcn_mfma_f32_16x16x32_bf16(ap, bv, o_acc[c], 0, 0, 0);
      }
    }
  }
  #pragma unroll
  for(int r = 0; r < 4; r++){
    float l = l_loc[r];
    #pragma unroll
    for(int off = 1; off < 16; off <<= 1) l += __shfl_xor(l, off);
    float invl = 1.f / l;
    long rowe = (long)b * 2048 + qt * 64 + wave * 16 + quad * 4 + r;
    #pragma unroll
    for(int c = 0; c < 8; c++)
      enc[rowe * 2048 + (kv * 2 + g) * 128 + c * 16 + l15] = f2b(o_acc[c][r] * invl);
  }
}

// ---------------------------------------------------------------------------
extern "C" void kernel_launch(void* const* d_in, const int* in_sizes, int n_in,
                              void* d_out, int out_size, void* d_ws, size_t ws_size,
                              hipStream_t stream){
  const float* x     = (const float*)d_in[0];
  const int*   posi  = (const int*)  d_in[1];
  // d_in[2] = attn_mask (causal, known analytically) -- unused
  const float* w_q   = (const float*)d_in[3];
  const float* w_kv  = (const float*)d_in[4];
  const float* w_out = (const float*)d_in[5];
  float* out = (float*)d_out;

  char* w = (char*)d_ws;                        // 78 MB used
  u16* xb     = (u16*)(w);                      // 16 MB (reused as enc after qkv)
  u16* wq_t   = (u16*)(w + 16777216);           //  8 MB [16][128][2048]
  u16* wkv_t  = (u16*)(w + 25165824);           //  8 MB [2][8][128][2048]
  u16* wout_t = (u16*)(w + 33554432);           //  8 MB [2048][2048]
  u16* q_buf  = (u16*)(w + 41943040);           // 16 MB [4096][2048]
  u16* k_buf  = (u16*)(w + 58720256);           //  8 MB [4096][1024]
  u16* v_t    = (u16*)(w + 67108864);           //  8 MB [2][8][128][2048]
  float* tab  = (float*)(w + 75497472);         //  2 MB sin/cos
  u16* enc    = xb;                             // xb dead after qkv

  k_prep    <<<12288, 256, 0, stream>>>(x, xb, w_q, wq_t, w_kv, wkv_t, w_out, wout_t, posi, tab);
  k_gemm_qkv<<<dim3(16, 16), 512, 0, stream>>>(xb, wq_t, wkv_t, tab, q_buf, k_buf, v_t);
  k_flash   <<<dim3(32, 32), 256, 0, stream>>>(q_buf, k_buf, v_t, enc);
  k_gemm_out<<<dim3(32, 16), 256, 0, stream>>>(enc, wout_t, out);
}